// Round 1
// baseline (649.198 us; speedup 1.0000x reference)
//
#include <hip/hip_runtime.h>

// ProbSparse attention (Informer) — B=4, L=2048, D=512, H=8, DK=64, SK=NTOP=40
// fp32 everywhere this round (top-k selection is numerically fragile).

constexpr int NB = 4;       // batch
constexpr int SEQ = 2048;   // L
constexpr int DM = 512;     // D
constexpr int NH = 8;
constexpr int DH = 64;      // DK
constexpr int NS = 40;      // SK (samples)
constexpr int NT = 40;      // NTOP
constexpr int ROWS = NB * SEQ;          // 8192
constexpr int BHROWS = NB * NH * SEQ;   // 65536

// ---------------------------------------------------------------------------
// Tiled fp32 GEMM: C(8192x512) = X(8192x512) @ W(512x512) + bias
// SPLIT=true scatters output to (B,H,L,DH) layout; else row-major (rows,512).
// ---------------------------------------------------------------------------
template <bool SPLIT>
__global__ __launch_bounds__(256) void gemm512(const float* __restrict__ X,
                                               const float* __restrict__ W,
                                               const float* __restrict__ bias,
                                               float* __restrict__ out) {
  __shared__ float As[16][68];  // [k][m], pad 68 keeps float4 reads 16B-aligned, writes <=2-way
  __shared__ float Bs[16][64];  // [k][n]
  const int tid = threadIdx.x;
  const int row0 = blockIdx.x * 64;
  const int col0 = blockIdx.y * 64;
  const int tx = tid & 15, ty = tid >> 4;
  float acc[4][4] = {};

  for (int k0 = 0; k0 < DM; k0 += 16) {
#pragma unroll
    for (int i = 0; i < 4; i++) {
      int idx = tid + i * 256;           // 1024 elems
      int m = idx >> 4, k = idx & 15;    // k fastest -> 64B row chunks, coalesced-ish
      As[k][m] = X[(row0 + m) * DM + k0 + k];
    }
#pragma unroll
    for (int i = 0; i < 4; i++) {
      int idx = tid + i * 256;
      int kk = idx >> 6, n = idx & 63;   // n fastest -> fully coalesced
      Bs[kk][n] = W[(k0 + kk) * DM + col0 + n];
    }
    __syncthreads();
#pragma unroll
    for (int k = 0; k < 16; k++) {
      float4 a4 = *(const float4*)&As[k][ty * 4];
      float4 b4 = *(const float4*)&Bs[k][tx * 4];
      float av[4] = {a4.x, a4.y, a4.z, a4.w};
      float bv[4] = {b4.x, b4.y, b4.z, b4.w};
#pragma unroll
      for (int i = 0; i < 4; i++)
#pragma unroll
        for (int j = 0; j < 4; j++) acc[i][j] = fmaf(av[i], bv[j], acc[i][j]);
    }
    __syncthreads();
  }

  float4 bb = *(const float4*)&bias[col0 + tx * 4];
  float bv[4] = {bb.x, bb.y, bb.z, bb.w};
#pragma unroll
  for (int i = 0; i < 4; i++) {
    int row = row0 + ty * 4 + i;
    float4 r = make_float4(acc[i][0] + bv[0], acc[i][1] + bv[1],
                           acc[i][2] + bv[2], acc[i][3] + bv[3]);
    if (SPLIT) {
      int b = row >> 11, l = row & (SEQ - 1);
      int h = col0 >> 6;  // BN=64 => one head per block column
      *(float4*)&out[((size_t)(b * NH + h) * SEQ + l) * DH + tx * 4] = r;
    } else {
      *(float4*)&out[(size_t)row * DM + col0 + tx * 4] = r;
    }
  }
}

// ---------------------------------------------------------------------------
// M[b,h,q] = max_j(Q[bhq]·K[bh,idx[q,j]]) - sum_j(...)/SEQ.  One wave per row.
// ---------------------------------------------------------------------------
__global__ __launch_bounds__(256) void m_kernel(const float* __restrict__ Q,
                                                const float* __restrict__ K,
                                                const int* __restrict__ idxs,
                                                float* __restrict__ M) {
  const int lane = threadIdx.x & 63;
  const int r = blockIdx.x * 4 + (threadIdx.x >> 6);  // [0, BHROWS)
  const int q = r & (SEQ - 1);
  const float qv = Q[(size_t)r * DH + lane];
  const float* Kbh = K + (size_t)(r >> 11) * SEQ * DH;
  float mx = -1e30f, sm = 0.f;
  for (int j = 0; j < NS; j++) {
    int ks = idxs[q * NS + j];
    float p = qv * Kbh[(size_t)ks * DH + lane];
#pragma unroll
    for (int o = 32; o; o >>= 1) p += __shfl_xor(p, o, 64);
    mx = fmaxf(mx, p);
    sm += p;
  }
  if (lane == 0) M[r] = mx - sm * (1.0f / (float)SEQ);
}

// ---------------------------------------------------------------------------
// Top-40 of M per (b,h); also builds selected-row mask. One block per (b,h).
// Tie-break: lower index (matches jax.lax.top_k).
// ---------------------------------------------------------------------------
__global__ __launch_bounds__(256) void topk_kernel(const float* __restrict__ M,
                                                   int* __restrict__ Mtop,
                                                   int* __restrict__ mask) {
  __shared__ float vals[SEQ];
  __shared__ float rv[256];
  __shared__ int ri[256];
  const int bh = blockIdx.x, tid = threadIdx.x;
  for (int i = tid; i < SEQ; i += 256) {
    vals[i] = M[bh * SEQ + i];
    mask[bh * SEQ + i] = 0;
  }
  __syncthreads();
  for (int it = 0; it < NT; it++) {
    float bm = -1e30f;
    int bi = 0x7fffffff;
    for (int i = tid; i < SEQ; i += 256) {
      float v = vals[i];
      if (v > bm) { bm = v; bi = i; }
    }
    rv[tid] = bm; ri[tid] = bi;
    __syncthreads();
    for (int s = 128; s > 0; s >>= 1) {
      if (tid < s) {
        if (rv[tid + s] > rv[tid] ||
            (rv[tid + s] == rv[tid] && ri[tid + s] < ri[tid])) {
          rv[tid] = rv[tid + s];
          ri[tid] = ri[tid + s];
        }
      }
      __syncthreads();
    }
    if (tid == 0) {
      int w = ri[0];
      Mtop[bh * NT + it] = w;
      mask[bh * SEQ + w] = 1;
      vals[w] = -1e30f;
    }
    __syncthreads();
  }
}

// ---------------------------------------------------------------------------
// V_sum[b,h,:] = sum_l V[b,h,l,:].  One block per (b,h).
// ---------------------------------------------------------------------------
__global__ __launch_bounds__(256) void vsum_kernel(const float* __restrict__ V,
                                                   float* __restrict__ Vsum) {
  __shared__ float part[4][DH];
  const int bh = blockIdx.x, tid = threadIdx.x;
  const int dk = tid & 63, p = tid >> 6;
  const float* Vb = V + (size_t)bh * SEQ * DH;
  float s = 0.f;
  for (int l = p; l < SEQ; l += 4) s += Vb[(size_t)l * DH + dk];
  part[p][dk] = s;
  __syncthreads();
  if (p == 0) Vsum[bh * DH + dk] = part[0][dk] + part[1][dk] + part[2][dk] + part[3][dk];
}

// ---------------------------------------------------------------------------
// ctxT (B,L,D) row-major: broadcast V_sum, zero at selected (b,h,l) slots
// (PV kernel atomically accumulates the attention rows there).
// ---------------------------------------------------------------------------
__global__ __launch_bounds__(256) void ctxinit_kernel(const float* __restrict__ Vsum,
                                                      const int* __restrict__ mask,
                                                      float* __restrict__ ctxT) {
  const int idx = blockIdx.x * 256 + threadIdx.x;  // float4 index
  const int f = idx * 4;
  const int d = f & (DM - 1), l = (f >> 9) & (SEQ - 1), b = f >> 20;
  const int h = d >> 6;
  float4 v = *(const float4*)&Vsum[b * DM + d];   // Vsum flat (B, H*DH) == (B, D)
  if (mask[(b * NH + h) * SEQ + l]) v = make_float4(0.f, 0.f, 0.f, 0.f);
  *(float4*)&ctxT[f] = v;
}

// ---------------------------------------------------------------------------
// scores[bh,u,s] = (Q[bh,Mtop[u]] · K[bh,s]) / 8.  Block: (bh, s-chunk of 256).
// ---------------------------------------------------------------------------
__global__ __launch_bounds__(256) void scores_kernel(const float* __restrict__ Q,
                                                     const float* __restrict__ K,
                                                     const int* __restrict__ Mtop,
                                                     float* __restrict__ scores) {
  __shared__ float Qs[NT * DH];
  const int bh = blockIdx.x, tid = threadIdx.x;
  for (int i = tid; i < NT * DH; i += 256) {
    int u = i >> 6, dk = i & 63;
    int row = Mtop[bh * NT + u];
    Qs[i] = Q[((size_t)bh * SEQ + row) * DH + dk];
  }
  __syncthreads();
  const int s = blockIdx.y * 256 + tid;
  const float* Krow = K + ((size_t)bh * SEQ + s) * DH;
  float4 kr[16];
#pragma unroll
  for (int g = 0; g < 16; g++) kr[g] = *(const float4*)&Krow[g * 4];
  for (int u = 0; u < NT; u++) {
    float acc = 0.f;
#pragma unroll
    for (int g = 0; g < 16; g++) {
      float4 qv = *(const float4*)&Qs[u * DH + g * 4];
      acc = fmaf(qv.x, kr[g].x, acc);
      acc = fmaf(qv.y, kr[g].y, acc);
      acc = fmaf(qv.z, kr[g].z, acc);
      acc = fmaf(qv.w, kr[g].w, acc);
    }
    scores[((size_t)bh * NT + u) * SEQ + s] = acc * 0.125f;
  }
}

// ---------------------------------------------------------------------------
// Row softmax over 2048, in place. One block per (bh,u) row.
// ---------------------------------------------------------------------------
__global__ __launch_bounds__(256) void softmax_kernel(float* __restrict__ scores) {
  __shared__ float red[256];
  const int row = blockIdx.x, tid = threadIdx.x;
  float* p = scores + (size_t)row * SEQ;
  float4 v0 = *(const float4*)&p[tid * 4];
  float4 v1 = *(const float4*)&p[1024 + tid * 4];
  float mx = fmaxf(fmaxf(fmaxf(v0.x, v0.y), fmaxf(v0.z, v0.w)),
                   fmaxf(fmaxf(v1.x, v1.y), fmaxf(v1.z, v1.w)));
  red[tid] = mx;
  __syncthreads();
  for (int s = 128; s; s >>= 1) {
    if (tid < s) red[tid] = fmaxf(red[tid], red[tid + s]);
    __syncthreads();
  }
  mx = red[0];
  __syncthreads();
  v0.x = __expf(v0.x - mx); v0.y = __expf(v0.y - mx);
  v0.z = __expf(v0.z - mx); v0.w = __expf(v0.w - mx);
  v1.x = __expf(v1.x - mx); v1.y = __expf(v1.y - mx);
  v1.z = __expf(v1.z - mx); v1.w = __expf(v1.w - mx);
  float sm = v0.x + v0.y + v0.z + v0.w + v1.x + v1.y + v1.z + v1.w;
  red[tid] = sm;
  __syncthreads();
  for (int s = 128; s; s >>= 1) {
    if (tid < s) red[tid] += red[tid + s];
    __syncthreads();
  }
  float inv = 1.0f / red[0];
  v0.x *= inv; v0.y *= inv; v0.z *= inv; v0.w *= inv;
  v1.x *= inv; v1.y *= inv; v1.z *= inv; v1.w *= inv;
  *(float4*)&p[tid * 4] = v0;
  *(float4*)&p[1024 + tid * 4] = v1;
}

// ---------------------------------------------------------------------------
// upd = attn @ V, atomically accumulated straight into ctxT at selected rows.
// Block: (bh, s-chunk of 256). 4 waves; thread (wid,dk) owns u = wid+4i.
// ---------------------------------------------------------------------------
__global__ __launch_bounds__(256) void pv_kernel(const float* __restrict__ attn,
                                                 const float* __restrict__ V,
                                                 const int* __restrict__ Mtop,
                                                 float* __restrict__ ctxT) {
  __shared__ float Vl[64 * DH];     // [sj][dk]
  __shared__ float Al[NT * 64];     // [u][sj]
  const int bh = blockIdx.x, tid = threadIdx.x;
  const int s0 = blockIdx.y * 256;
  const int wid = tid >> 6, dk = tid & 63;
  float acc[10] = {};

  for (int st = 0; st < 4; st++) {
    const int sb = s0 + st * 64;
    __syncthreads();
#pragma unroll
    for (int i = 0; i < 16; i++) {
      int idx = tid + i * 256;  // 4096
      int sj = idx >> 6, d2 = idx & 63;
      Vl[idx] = V[((size_t)bh * SEQ + sb + sj) * DH + d2];
    }
#pragma unroll
    for (int i = 0; i < 10; i++) {
      int idx = tid + i * 256;  // 2560
      int u = idx >> 6, sj = idx & 63;
      Al[idx] = attn[((size_t)bh * NT + u) * SEQ + sb + sj];
    }
    __syncthreads();
    for (int g = 0; g < 16; g++) {
      float a[10][4];
#pragma unroll
      for (int i = 0; i < 10; i++) {
        float4 t = *(const float4*)&Al[(wid + 4 * i) * 64 + g * 4];  // wave-broadcast
        a[i][0] = t.x; a[i][1] = t.y; a[i][2] = t.z; a[i][3] = t.w;
      }
#pragma unroll
      for (int t = 0; t < 4; t++) {
        float v = Vl[(g * 4 + t) * DH + dk];
#pragma unroll
        for (int i = 0; i < 10; i++) acc[i] = fmaf(a[i][t], v, acc[i]);
      }
    }
  }

  const int b = bh >> 3, h = bh & 7;
#pragma unroll
  for (int i = 0; i < 10; i++) {
    int u = wid + 4 * i;
    int row = Mtop[bh * NT + u];
    atomicAdd(&ctxT[((size_t)b * SEQ + row) * DM + h * DH + dk], acc[i]);
  }
}

// ---------------------------------------------------------------------------
extern "C" void kernel_launch(void* const* d_in, const int* in_sizes, int n_in,
                              void* d_out, int out_size, void* d_ws, size_t ws_size,
                              hipStream_t stream) {
  (void)in_sizes; (void)n_in; (void)out_size; (void)ws_size;
  const float* queries = (const float*)d_in[0];
  const float* keys    = (const float*)d_in[1];
  const float* values  = (const float*)d_in[2];
  // d_in[3] attn_mask: unused by the reference
  const int* index_sample = (const int*)d_in[4];
  const float* Wq = (const float*)d_in[5];
  const float* bq = (const float*)d_in[6];
  const float* Wk = (const float*)d_in[7];
  const float* bk = (const float*)d_in[8];
  const float* Wv = (const float*)d_in[9];
  const float* bv = (const float*)d_in[10];
  const float* Wo = (const float*)d_in[11];
  const float* bo = (const float*)d_in[12];
  float* out = (float*)d_out;

  // workspace carve-up (floats): Q,K,V,ctxT 4x 4,194,304; scores 2,621,440;
  // M 65,536; Vsum 2,048; Mtop 1,280 ints; mask 65,536 ints  => ~78.1 MB
  float* ws = (float*)d_ws;
  float* Q    = ws;
  float* Kp   = Q + (size_t)ROWS * DM;
  float* Vp   = Kp + (size_t)ROWS * DM;
  float* ctxT = Vp + (size_t)ROWS * DM;
  float* scores = ctxT + (size_t)ROWS * DM;
  float* M    = scores + (size_t)NB * NH * NT * SEQ;
  float* Vsum = M + BHROWS;
  int* Mtop   = (int*)(Vsum + NB * NH * DH);
  int* mask   = Mtop + NB * NH * NT;

  const dim3 gg(ROWS / 64, DM / 64);
  gemm512<true><<<gg, 256, 0, stream>>>(queries, Wq, bq, Q);
  gemm512<true><<<gg, 256, 0, stream>>>(keys, Wk, bk, Kp);
  gemm512<true><<<gg, 256, 0, stream>>>(values, Wv, bv, Vp);
  m_kernel<<<BHROWS / 4, 256, 0, stream>>>(Q, Kp, index_sample, M);
  topk_kernel<<<NB * NH, 256, 0, stream>>>(M, Mtop, mask);
  vsum_kernel<<<NB * NH, 256, 0, stream>>>(Vp, Vsum);
  ctxinit_kernel<<<(ROWS * DM / 4) / 256, 256, 0, stream>>>(Vsum, mask, ctxT);
  scores_kernel<<<dim3(NB * NH, SEQ / 256), 256, 0, stream>>>(Q, Kp, Mtop, scores);
  softmax_kernel<<<NB * NH * NT, 256, 0, stream>>>(scores);
  pv_kernel<<<dim3(NB * NH, SEQ / 256), 256, 0, stream>>>(scores, Vp, Mtop, ctxT);
  gemm512<false><<<gg, 256, 0, stream>>>(ctxT, Wo, bo, out);
}

// Round 3
// 490.301 us; speedup vs baseline: 1.3241x; 1.3241x over previous
//
#include <hip/hip_runtime.h>

// ProbSparse attention (Informer) — B=4, L=2048, D=512, H=8, DK=64, SK=NTOP=40
// fp32 everywhere (top-k selection is numerically fragile).
// Round 3: fully deterministic — no atomics, no mask; scatter via overwrite.

constexpr int NB = 4;       // batch
constexpr int SEQ = 2048;   // L
constexpr int DM = 512;     // D
constexpr int NH = 8;
constexpr int DH = 64;      // DK
constexpr int NS = 40;      // SK (samples)
constexpr int NT = 40;      // NTOP
constexpr int ROWS = NB * SEQ;          // 8192
constexpr int BHROWS = NB * NH * SEQ;   // 65536
constexpr int NSC = 8;      // s-chunks in pv (SEQ/256)

// ---------------------------------------------------------------------------
// Tiled fp32 GEMM: C(8192x512) = X(8192x512) @ W(512x512) + bias
// 128(M) x 64(N) tile, BK=16, 256 threads, 8x4 per thread, reg-prefetch.
// SPLIT=true scatters output to (B,H,L,DH) layout; else row-major (rows,512).
// ---------------------------------------------------------------------------
template <bool SPLIT>
__global__ __launch_bounds__(256) void gemm128(const float* __restrict__ X,
                                               const float* __restrict__ W,
                                               const float* __restrict__ bias,
                                               float* __restrict__ out) {
  __shared__ float As[16][128];  // [k][m]
  __shared__ float Bs[16][64];   // [k][n]
  const int tid = threadIdx.x;
  const int row0 = blockIdx.x * 128;
  const int col0 = blockIdx.y * 64;
  const int tx = tid & 15, ty = tid >> 4;   // tx: n/4, ty: m/8
  float acc[8][4] = {};

  const int am0 = tid >> 2, akq = (tid & 3) * 4;
  const int bn = (tid & 15) * 4, bk = tid >> 4;

  float4 aR[2], bR;
  {
    const float* xa = X + (size_t)(row0 + am0) * DM + akq;
    aR[0] = *(const float4*)xa;
    aR[1] = *(const float4*)(xa + 64 * DM);  // m += 64 for i=1
    bR = *(const float4*)&W[(size_t)bk * DM + col0 + bn];
  }

  for (int k0 = 0; k0 < DM; k0 += 16) {
    __syncthreads();
#pragma unroll
    for (int i = 0; i < 2; i++) {
      int m = am0 + i * 64;
      As[akq + 0][m] = aR[i].x;
      As[akq + 1][m] = aR[i].y;
      As[akq + 2][m] = aR[i].z;
      As[akq + 3][m] = aR[i].w;
    }
    *(float4*)&Bs[bk][bn] = bR;
    __syncthreads();

    if (k0 + 16 < DM) {
      const float* xa = X + (size_t)(row0 + am0) * DM + k0 + 16 + akq;
      aR[0] = *(const float4*)xa;
      aR[1] = *(const float4*)(xa + 64 * DM);
      bR = *(const float4*)&W[(size_t)(k0 + 16 + bk) * DM + col0 + bn];
    }

#pragma unroll
    for (int k = 0; k < 16; k++) {
      float4 a0 = *(const float4*)&As[k][ty * 8];
      float4 a1 = *(const float4*)&As[k][ty * 8 + 4];
      float4 b4 = *(const float4*)&Bs[k][tx * 4];
      float av[8] = {a0.x, a0.y, a0.z, a0.w, a1.x, a1.y, a1.z, a1.w};
      float bv[4] = {b4.x, b4.y, b4.z, b4.w};
#pragma unroll
      for (int i = 0; i < 8; i++)
#pragma unroll
        for (int j = 0; j < 4; j++) acc[i][j] = fmaf(av[i], bv[j], acc[i][j]);
    }
  }

  float4 bb = *(const float4*)&bias[col0 + tx * 4];
  float bv[4] = {bb.x, bb.y, bb.z, bb.w};
#pragma unroll
  for (int i = 0; i < 8; i++) {
    int row = row0 + ty * 8 + i;
    float4 r = make_float4(acc[i][0] + bv[0], acc[i][1] + bv[1],
                           acc[i][2] + bv[2], acc[i][3] + bv[3]);
    if (SPLIT) {
      int b = row >> 11, l = row & (SEQ - 1);
      int h = col0 >> 6;  // BN=64 => one head per block column
      *(float4*)&out[((size_t)(b * NH + h) * SEQ + l) * DH + tx * 4] = r;
    } else {
      *(float4*)&out[(size_t)row * DM + col0 + tx * 4] = r;
    }
  }
}

// ---------------------------------------------------------------------------
// M[b,h,q] = max_j(Q[bhq]·K[bh,idx[q,j]]) - sum_j(...)/SEQ.  One wave per row.
// 8 lane-groups of 8; group g handles samples j = g + 8p (p=0..4).
// ---------------------------------------------------------------------------
__global__ __launch_bounds__(256) void m_kernel(const float* __restrict__ Q,
                                                const float* __restrict__ K,
                                                const int* __restrict__ idxs,
                                                float* __restrict__ M) {
  const int lane = threadIdx.x & 63;
  const int r = blockIdx.x * 4 + (threadIdx.x >> 6);  // [0, BHROWS)
  const int q = r & (SEQ - 1);
  const int g = lane >> 3;        // sample group 0..7
  const int d8 = (lane & 7) * 8;  // dim slice start
  const float* Qr = Q + (size_t)r * DH + d8;
  const float4 q0 = *(const float4*)Qr;
  const float4 q1 = *(const float4*)(Qr + 4);
  const float* Kbh = K + (size_t)(r >> 11) * SEQ * DH;

  int ks[5];
#pragma unroll
  for (int p = 0; p < 5; p++) ks[p] = idxs[q * NS + g + 8 * p];
  float4 k0[5], k1[5];
#pragma unroll
  for (int p = 0; p < 5; p++) {
    const float* Kr = Kbh + (size_t)ks[p] * DH + d8;
    k0[p] = *(const float4*)Kr;
    k1[p] = *(const float4*)(Kr + 4);
  }
  float mx = -1e30f, sm = 0.f;
#pragma unroll
  for (int p = 0; p < 5; p++) {
    float acc = q0.x * k0[p].x + q0.y * k0[p].y + q0.z * k0[p].z + q0.w * k0[p].w +
                q1.x * k1[p].x + q1.y * k1[p].y + q1.z * k1[p].z + q1.w * k1[p].w;
    acc += __shfl_xor(acc, 1, 64);
    acc += __shfl_xor(acc, 2, 64);
    acc += __shfl_xor(acc, 4, 64);
    mx = fmaxf(mx, acc);
    sm += acc;
  }
#pragma unroll
  for (int o = 8; o <= 32; o <<= 1) {
    mx = fmaxf(mx, __shfl_xor(mx, o, 64));
    sm += __shfl_xor(sm, o, 64);
  }
  if (lane == 0) M[r] = mx - sm * (1.0f / (float)SEQ);
}

// ---------------------------------------------------------------------------
// Top-40 of M per (b,h). One block per (b,h). Wave-shuffle argmax;
// 2 barriers per iteration. Tie-break: lower index (matches jax top_k).
// ---------------------------------------------------------------------------
__global__ __launch_bounds__(256) void topk_kernel(const float* __restrict__ M,
                                                   int* __restrict__ Mtop) {
  __shared__ float vals[SEQ];
  __shared__ float wv[4];
  __shared__ int wi[4];
  const int bh = blockIdx.x, tid = threadIdx.x;
  const int lane = tid & 63, wid = tid >> 6;
  for (int i = tid; i < SEQ; i += 256) vals[i] = M[bh * SEQ + i];
  __syncthreads();
  for (int it = 0; it < NT; it++) {
    float bm = -1e30f;
    int bi = 0x7fffffff;
    for (int i = tid; i < SEQ; i += 256) {
      float v = vals[i];
      if (v > bm) { bm = v; bi = i; }
    }
#pragma unroll
    for (int o = 1; o <= 32; o <<= 1) {
      float ov = __shfl_xor(bm, o, 64);
      int oi = __shfl_xor(bi, o, 64);
      if (ov > bm || (ov == bm && oi < bi)) { bm = ov; bi = oi; }
    }
    if (lane == 0) { wv[wid] = bm; wi[wid] = bi; }
    __syncthreads();
    if (tid == 0) {
      float fm = wv[0];
      int fi = wi[0];
#pragma unroll
      for (int w = 1; w < 4; w++) {
        if (wv[w] > fm || (wv[w] == fm && wi[w] < fi)) { fm = wv[w]; fi = wi[w]; }
      }
      Mtop[bh * NT + it] = fi;
      vals[fi] = -1e30f;
    }
    __syncthreads();
  }
}

// ---------------------------------------------------------------------------
// V_sum[b,h,:] = sum_l V[b,h,l,:].  One block per (b,h).
// ---------------------------------------------------------------------------
__global__ __launch_bounds__(256) void vsum_kernel(const float* __restrict__ V,
                                                   float* __restrict__ Vsum) {
  __shared__ float part[4][DH];
  const int bh = blockIdx.x, tid = threadIdx.x;
  const int dk = tid & 63, p = tid >> 6;
  const float* Vb = V + (size_t)bh * SEQ * DH;
  float s = 0.f;
  for (int l = p; l < SEQ; l += 4) s += Vb[(size_t)l * DH + dk];
  part[p][dk] = s;
  __syncthreads();
  if (p == 0) Vsum[bh * DH + dk] = part[0][dk] + part[1][dk] + part[2][dk] + part[3][dk];
}

// ---------------------------------------------------------------------------
// ctxT (B,L,D) row-major: pure V_sum broadcast (selected rows overwritten
// later by reduce_scatter).
// ---------------------------------------------------------------------------
__global__ __launch_bounds__(256) void ctxinit_kernel(const float* __restrict__ Vsum,
                                                      float* __restrict__ ctxT) {
  const int idx = blockIdx.x * 256 + threadIdx.x;  // float4 index
  const int f = idx * 4;
  const int d = f & (DM - 1), b = f >> 20;
  float4 v = *(const float4*)&Vsum[b * DM + d];   // Vsum flat (B, H*DH) == (B, D)
  *(float4*)&ctxT[f] = v;
}

// ---------------------------------------------------------------------------
// scores[bh,u,s] = (Q[bh,Mtop[u]] · K[bh,s]) / 8.  Block: (bh, s-chunk of 256).
// ---------------------------------------------------------------------------
__global__ __launch_bounds__(256) void scores_kernel(const float* __restrict__ Q,
                                                     const float* __restrict__ K,
                                                     const int* __restrict__ Mtop,
                                                     float* __restrict__ scores) {
  __shared__ float Qs[NT * DH];
  const int bh = blockIdx.x, tid = threadIdx.x;
  for (int i = tid; i < NT * DH; i += 256) {
    int u = i >> 6, dk = i & 63;
    int row = Mtop[bh * NT + u];
    Qs[i] = Q[((size_t)bh * SEQ + row) * DH + dk];
  }
  __syncthreads();
  const int s = blockIdx.y * 256 + tid;
  const float* Krow = K + ((size_t)bh * SEQ + s) * DH;
  float4 kr[16];
#pragma unroll
  for (int g = 0; g < 16; g++) kr[g] = *(const float4*)&Krow[g * 4];
  for (int u = 0; u < NT; u++) {
    float acc = 0.f;
#pragma unroll
    for (int g = 0; g < 16; g++) {
      float4 qv = *(const float4*)&Qs[u * DH + g * 4];
      acc = fmaf(qv.x, kr[g].x, acc);
      acc = fmaf(qv.y, kr[g].y, acc);
      acc = fmaf(qv.z, kr[g].z, acc);
      acc = fmaf(qv.w, kr[g].w, acc);
    }
    scores[((size_t)bh * NT + u) * SEQ + s] = acc * 0.125f;
  }
}

// ---------------------------------------------------------------------------
// Row softmax over 2048, in place. One block per (bh,u) row.
// ---------------------------------------------------------------------------
__global__ __launch_bounds__(256) void softmax_kernel(float* __restrict__ scores) {
  __shared__ float red[256];
  const int row = blockIdx.x, tid = threadIdx.x;
  float* p = scores + (size_t)row * SEQ;
  float4 v0 = *(const float4*)&p[tid * 4];
  float4 v1 = *(const float4*)&p[1024 + tid * 4];
  float mx = fmaxf(fmaxf(fmaxf(v0.x, v0.y), fmaxf(v0.z, v0.w)),
                   fmaxf(fmaxf(v1.x, v1.y), fmaxf(v1.z, v1.w)));
  red[tid] = mx;
  __syncthreads();
  for (int s = 128; s; s >>= 1) {
    if (tid < s) red[tid] = fmaxf(red[tid], red[tid + s]);
    __syncthreads();
  }
  mx = red[0];
  __syncthreads();
  v0.x = __expf(v0.x - mx); v0.y = __expf(v0.y - mx);
  v0.z = __expf(v0.z - mx); v0.w = __expf(v0.w - mx);
  v1.x = __expf(v1.x - mx); v1.y = __expf(v1.y - mx);
  v1.z = __expf(v1.z - mx); v1.w = __expf(v1.w - mx);
  float sm = v0.x + v0.y + v0.z + v0.w + v1.x + v1.y + v1.z + v1.w;
  red[tid] = sm;
  __syncthreads();
  for (int s = 128; s; s >>= 1) {
    if (tid < s) red[tid] += red[tid + s];
    __syncthreads();
  }
  float inv = 1.0f / red[0];
  v0.x *= inv; v0.y *= inv; v0.z *= inv; v0.w *= inv;
  v1.x *= inv; v1.y *= inv; v1.z *= inv; v1.w *= inv;
  *(float4*)&p[tid * 4] = v0;
  *(float4*)&p[1024 + tid * 4] = v1;
}

// ---------------------------------------------------------------------------
// Partial upd = attn @ V over one 256-wide s-chunk. No atomics.
// updp[((bh*NSC+sc)*NT + u)*DH + dk]. Block: (bh, sc). 4 waves, u=wid+4i.
// ---------------------------------------------------------------------------
__global__ __launch_bounds__(256) void pv_partial_kernel(const float* __restrict__ attn,
                                                         const float* __restrict__ V,
                                                         float* __restrict__ updp) {
  __shared__ float Vl[64 * DH];     // [sj][dk]
  __shared__ float Al[NT * 64];     // [u][sj]
  const int bh = blockIdx.x, sc = blockIdx.y, tid = threadIdx.x;
  const int s0 = sc * 256;
  const int wid = tid >> 6, dk = tid & 63;
  float acc[10] = {};

  for (int st = 0; st < 4; st++) {
    const int sb = s0 + st * 64;
    __syncthreads();
#pragma unroll
    for (int i = 0; i < 16; i++) {
      int idx = tid + i * 256;  // 4096
      int sj = idx >> 6, d2 = idx & 63;
      Vl[idx] = V[((size_t)bh * SEQ + sb + sj) * DH + d2];
    }
#pragma unroll
    for (int i = 0; i < 10; i++) {
      int idx = tid + i * 256;  // 2560
      int u = idx >> 6, sj = idx & 63;
      Al[idx] = attn[((size_t)bh * NT + u) * SEQ + sb + sj];
    }
    __syncthreads();
    for (int g = 0; g < 16; g++) {
      float a[10][4];
#pragma unroll
      for (int i = 0; i < 10; i++) {
        float4 t = *(const float4*)&Al[(wid + 4 * i) * 64 + g * 4];  // wave-broadcast
        a[i][0] = t.x; a[i][1] = t.y; a[i][2] = t.z; a[i][3] = t.w;
      }
#pragma unroll
      for (int t = 0; t < 4; t++) {
        float v = Vl[(g * 4 + t) * DH + dk];
#pragma unroll
        for (int i = 0; i < 10; i++) acc[i] = fmaf(a[i][t], v, acc[i]);
      }
    }
  }

#pragma unroll
  for (int i = 0; i < 10; i++) {
    int u = wid + 4 * i;
    updp[((size_t)(bh * NSC + sc) * NT + u) * DH + dk] = acc[i];
  }
}

// ---------------------------------------------------------------------------
// Sum the NSC partials in fixed order, overwrite selected ctxT rows.
// Grid (32 bh, 10); thread (tid>>6 -> u sub, tid&63 -> dk). Deterministic:
// distinct rows per (b,h), distinct head-slices across h.
// ---------------------------------------------------------------------------
__global__ __launch_bounds__(256) void reduce_scatter_kernel(const float* __restrict__ updp,
                                                             const int* __restrict__ Mtop,
                                                             float* __restrict__ ctxT) {
  const int bh = blockIdx.x;
  const int u = blockIdx.y * 4 + (threadIdx.x >> 6);
  const int dk = threadIdx.x & 63;
  float s = 0.f;
#pragma unroll
  for (int sc = 0; sc < NSC; sc++)
    s += updp[((size_t)(bh * NSC + sc) * NT + u) * DH + dk];
  const int row = Mtop[bh * NT + u];
  const int b = bh >> 3, h = bh & 7;
  ctxT[((size_t)b * SEQ + row) * DM + h * DH + dk] = s;
}

// ---------------------------------------------------------------------------
extern "C" void kernel_launch(void* const* d_in, const int* in_sizes, int n_in,
                              void* d_out, int out_size, void* d_ws, size_t ws_size,
                              hipStream_t stream) {
  (void)in_sizes; (void)n_in; (void)out_size; (void)ws_size;
  const float* queries = (const float*)d_in[0];
  const float* keys    = (const float*)d_in[1];
  const float* values  = (const float*)d_in[2];
  // d_in[3] attn_mask: unused by the reference
  const int* index_sample = (const int*)d_in[4];
  const float* Wq = (const float*)d_in[5];
  const float* bq = (const float*)d_in[6];
  const float* Wk = (const float*)d_in[7];
  const float* bk = (const float*)d_in[8];
  const float* Wv = (const float*)d_in[9];
  const float* bv = (const float*)d_in[10];
  const float* Wo = (const float*)d_in[11];
  const float* bo = (const float*)d_in[12];
  float* out = (float*)d_out;

  // workspace carve-up (floats): Q,K,V,ctxT 4x 4,194,304; scores 2,621,440;
  // M 65,536; Vsum 2,048; Mtop 1,280 ints  => ~78 MB.
  // updp (655,360 floats) aliases Q, which is dead after scores_kernel.
  float* ws = (float*)d_ws;
  float* Q    = ws;
  float* Kp   = Q + (size_t)ROWS * DM;
  float* Vp   = Kp + (size_t)ROWS * DM;
  float* ctxT = Vp + (size_t)ROWS * DM;
  float* scores = ctxT + (size_t)ROWS * DM;
  float* M    = scores + (size_t)NB * NH * NT * SEQ;
  float* Vsum = M + BHROWS;
  int* Mtop   = (int*)(Vsum + NB * NH * DH);
  float* updp = Q;  // reuse: Q dead after scores_kernel

  const dim3 gg(ROWS / 128, DM / 64);
  gemm128<true><<<gg, 256, 0, stream>>>(queries, Wq, bq, Q);
  gemm128<true><<<gg, 256, 0, stream>>>(keys, Wk, bk, Kp);
  gemm128<true><<<gg, 256, 0, stream>>>(values, Wv, bv, Vp);
  m_kernel<<<BHROWS / 4, 256, 0, stream>>>(Q, Kp, index_sample, M);
  topk_kernel<<<NB * NH, 256, 0, stream>>>(M, Mtop);
  vsum_kernel<<<NB * NH, 256, 0, stream>>>(Vp, Vsum);
  ctxinit_kernel<<<(ROWS * DM / 4) / 256, 256, 0, stream>>>(Vsum, ctxT);
  scores_kernel<<<dim3(NB * NH, SEQ / 256), 256, 0, stream>>>(Q, Kp, Mtop, scores);
  softmax_kernel<<<NB * NH * NT, 256, 0, stream>>>(scores);
  pv_partial_kernel<<<dim3(NB * NH, NSC), 256, 0, stream>>>(scores, Vp, updp);
  reduce_scatter_kernel<<<dim3(NB * NH, NT / 4), 256, 0, stream>>>(updp, Mtop, ctxT);
  gemm128<false><<<gg, 256, 0, stream>>>(ctxT, Wo, bo, out);
}

// Round 4
// 381.465 us; speedup vs baseline: 1.7019x; 1.2853x over previous
//
#include <hip/hip_runtime.h>

// ProbSparse attention (Informer) — B=4, L=2048, D=512, H=8, DK=64, SK=NTOP=40
// fp32 everywhere (top-k selection is numerically fragile).
// Round 4: two-stage V_sum (round-3 vsum was 122us at 1.4% occupancy).

constexpr int NB = 4;       // batch
constexpr int SEQ = 2048;   // L
constexpr int DM = 512;     // D
constexpr int NH = 8;
constexpr int DH = 64;      // DK
constexpr int NS = 40;      // SK (samples)
constexpr int NT = 40;      // NTOP
constexpr int ROWS = NB * SEQ;          // 8192
constexpr int BHROWS = NB * NH * SEQ;   // 65536
constexpr int NSC = 8;      // s-chunks in pv (SEQ/256)
constexpr int VCH = 16;     // vsum l-chunks per (b,h)

// ---------------------------------------------------------------------------
// Tiled fp32 GEMM: C(8192x512) = X(8192x512) @ W(512x512) + bias
// 128(M) x 64(N) tile, BK=16, 256 threads, 8x4 per thread, reg-prefetch.
// SPLIT=true scatters output to (B,H,L,DH) layout; else row-major (rows,512).
// ---------------------------------------------------------------------------
template <bool SPLIT>
__global__ __launch_bounds__(256) void gemm128(const float* __restrict__ X,
                                               const float* __restrict__ W,
                                               const float* __restrict__ bias,
                                               float* __restrict__ out) {
  __shared__ float As[16][128];  // [k][m]
  __shared__ float Bs[16][64];   // [k][n]
  const int tid = threadIdx.x;
  const int row0 = blockIdx.x * 128;
  const int col0 = blockIdx.y * 64;
  const int tx = tid & 15, ty = tid >> 4;   // tx: n/4, ty: m/8
  float acc[8][4] = {};

  const int am0 = tid >> 2, akq = (tid & 3) * 4;
  const int bn = (tid & 15) * 4, bk = tid >> 4;

  float4 aR[2], bR;
  {
    const float* xa = X + (size_t)(row0 + am0) * DM + akq;
    aR[0] = *(const float4*)xa;
    aR[1] = *(const float4*)(xa + 64 * DM);  // m += 64 for i=1
    bR = *(const float4*)&W[(size_t)bk * DM + col0 + bn];
  }

  for (int k0 = 0; k0 < DM; k0 += 16) {
    __syncthreads();
#pragma unroll
    for (int i = 0; i < 2; i++) {
      int m = am0 + i * 64;
      As[akq + 0][m] = aR[i].x;
      As[akq + 1][m] = aR[i].y;
      As[akq + 2][m] = aR[i].z;
      As[akq + 3][m] = aR[i].w;
    }
    *(float4*)&Bs[bk][bn] = bR;
    __syncthreads();

    if (k0 + 16 < DM) {
      const float* xa = X + (size_t)(row0 + am0) * DM + k0 + 16 + akq;
      aR[0] = *(const float4*)xa;
      aR[1] = *(const float4*)(xa + 64 * DM);
      bR = *(const float4*)&W[(size_t)(k0 + 16 + bk) * DM + col0 + bn];
    }

#pragma unroll
    for (int k = 0; k < 16; k++) {
      float4 a0 = *(const float4*)&As[k][ty * 8];
      float4 a1 = *(const float4*)&As[k][ty * 8 + 4];
      float4 b4 = *(const float4*)&Bs[k][tx * 4];
      float av[8] = {a0.x, a0.y, a0.z, a0.w, a1.x, a1.y, a1.z, a1.w};
      float bv[4] = {b4.x, b4.y, b4.z, b4.w};
#pragma unroll
      for (int i = 0; i < 8; i++)
#pragma unroll
        for (int j = 0; j < 4; j++) acc[i][j] = fmaf(av[i], bv[j], acc[i][j]);
    }
  }

  float4 bb = *(const float4*)&bias[col0 + tx * 4];
  float bv[4] = {bb.x, bb.y, bb.z, bb.w};
#pragma unroll
  for (int i = 0; i < 8; i++) {
    int row = row0 + ty * 8 + i;
    float4 r = make_float4(acc[i][0] + bv[0], acc[i][1] + bv[1],
                           acc[i][2] + bv[2], acc[i][3] + bv[3]);
    if (SPLIT) {
      int b = row >> 11, l = row & (SEQ - 1);
      int h = col0 >> 6;  // BN=64 => one head per block column
      *(float4*)&out[((size_t)(b * NH + h) * SEQ + l) * DH + tx * 4] = r;
    } else {
      *(float4*)&out[(size_t)row * DM + col0 + tx * 4] = r;
    }
  }
}

// ---------------------------------------------------------------------------
// M[b,h,q] = max_j(Q[bhq]·K[bh,idx[q,j]]) - sum_j(...)/SEQ.  One wave per row.
// 8 lane-groups of 8; group g handles samples j = g + 8p (p=0..4).
// ---------------------------------------------------------------------------
__global__ __launch_bounds__(256) void m_kernel(const float* __restrict__ Q,
                                                const float* __restrict__ K,
                                                const int* __restrict__ idxs,
                                                float* __restrict__ M) {
  const int lane = threadIdx.x & 63;
  const int r = blockIdx.x * 4 + (threadIdx.x >> 6);  // [0, BHROWS)
  const int q = r & (SEQ - 1);
  const int g = lane >> 3;        // sample group 0..7
  const int d8 = (lane & 7) * 8;  // dim slice start
  const float* Qr = Q + (size_t)r * DH + d8;
  const float4 q0 = *(const float4*)Qr;
  const float4 q1 = *(const float4*)(Qr + 4);
  const float* Kbh = K + (size_t)(r >> 11) * SEQ * DH;

  int ks[5];
#pragma unroll
  for (int p = 0; p < 5; p++) ks[p] = idxs[q * NS + g + 8 * p];
  float4 k0[5], k1[5];
#pragma unroll
  for (int p = 0; p < 5; p++) {
    const float* Kr = Kbh + (size_t)ks[p] * DH + d8;
    k0[p] = *(const float4*)Kr;
    k1[p] = *(const float4*)(Kr + 4);
  }
  float mx = -1e30f, sm = 0.f;
#pragma unroll
  for (int p = 0; p < 5; p++) {
    float acc = q0.x * k0[p].x + q0.y * k0[p].y + q0.z * k0[p].z + q0.w * k0[p].w +
                q1.x * k1[p].x + q1.y * k1[p].y + q1.z * k1[p].z + q1.w * k1[p].w;
    acc += __shfl_xor(acc, 1, 64);
    acc += __shfl_xor(acc, 2, 64);
    acc += __shfl_xor(acc, 4, 64);
    mx = fmaxf(mx, acc);
    sm += acc;
  }
#pragma unroll
  for (int o = 8; o <= 32; o <<= 1) {
    mx = fmaxf(mx, __shfl_xor(mx, o, 64));
    sm += __shfl_xor(sm, o, 64);
  }
  if (lane == 0) M[r] = mx - sm * (1.0f / (float)SEQ);
}

// ---------------------------------------------------------------------------
// Top-40 of M per (b,h). One block per (b,h). Wave-shuffle argmax;
// 2 barriers per iteration. Tie-break: lower index (matches jax top_k).
// ---------------------------------------------------------------------------
__global__ __launch_bounds__(256) void topk_kernel(const float* __restrict__ M,
                                                   int* __restrict__ Mtop) {
  __shared__ float vals[SEQ];
  __shared__ float wv[4];
  __shared__ int wi[4];
  const int bh = blockIdx.x, tid = threadIdx.x;
  const int lane = tid & 63, wid = tid >> 6;
  for (int i = tid; i < SEQ; i += 256) vals[i] = M[bh * SEQ + i];
  __syncthreads();
  for (int it = 0; it < NT; it++) {
    float bm = -1e30f;
    int bi = 0x7fffffff;
    for (int i = tid; i < SEQ; i += 256) {
      float v = vals[i];
      if (v > bm) { bm = v; bi = i; }
    }
#pragma unroll
    for (int o = 1; o <= 32; o <<= 1) {
      float ov = __shfl_xor(bm, o, 64);
      int oi = __shfl_xor(bi, o, 64);
      if (ov > bm || (ov == bm && oi < bi)) { bm = ov; bi = oi; }
    }
    if (lane == 0) { wv[wid] = bm; wi[wid] = bi; }
    __syncthreads();
    if (tid == 0) {
      float fm = wv[0];
      int fi = wi[0];
#pragma unroll
      for (int w = 1; w < 4; w++) {
        if (wv[w] > fm || (wv[w] == fm && wi[w] < fi)) { fm = wv[w]; fi = wi[w]; }
      }
      Mtop[bh * NT + it] = fi;
      vals[fi] = -1e30f;
    }
    __syncthreads();
  }
}

// ---------------------------------------------------------------------------
// V_sum stage 1: partial[bh][c][dk] = sum of 128 rows. Grid (32, 16).
// ---------------------------------------------------------------------------
__global__ __launch_bounds__(256) void vsum1_kernel(const float* __restrict__ V,
                                                    float* __restrict__ part) {
  __shared__ float sm[4][DH];
  const int bh = blockIdx.x, c = blockIdx.y, tid = threadIdx.x;
  const int dk = tid & 63, p = tid >> 6;
  const float* Vb = V + ((size_t)bh * SEQ + c * (SEQ / VCH)) * DH;
  float s = 0.f;
  for (int l = p; l < SEQ / VCH; l += 4) s += Vb[(size_t)l * DH + dk];
  sm[p][dk] = s;
  __syncthreads();
  if (p == 0)
    part[(size_t)(bh * VCH + c) * DH + dk] = sm[0][dk] + sm[1][dk] + sm[2][dk] + sm[3][dk];
}

// ---------------------------------------------------------------------------
// V_sum stage 2: fixed-order sum of the 16 partials. Grid 32, block 64.
// ---------------------------------------------------------------------------
__global__ __launch_bounds__(64) void vsum2_kernel(const float* __restrict__ part,
                                                   float* __restrict__ Vsum) {
  const int bh = blockIdx.x, dk = threadIdx.x;
  float s = 0.f;
#pragma unroll
  for (int c = 0; c < VCH; c++) s += part[(size_t)(bh * VCH + c) * DH + dk];
  Vsum[bh * DH + dk] = s;
}

// ---------------------------------------------------------------------------
// ctxT (B,L,D) row-major: pure V_sum broadcast (selected rows overwritten
// later by reduce_scatter).
// ---------------------------------------------------------------------------
__global__ __launch_bounds__(256) void ctxinit_kernel(const float* __restrict__ Vsum,
                                                      float* __restrict__ ctxT) {
  const int idx = blockIdx.x * 256 + threadIdx.x;  // float4 index
  const int f = idx * 4;
  const int d = f & (DM - 1), b = f >> 20;
  float4 v = *(const float4*)&Vsum[b * DM + d];   // Vsum flat (B, H*DH) == (B, D)
  *(float4*)&ctxT[f] = v;
}

// ---------------------------------------------------------------------------
// scores[bh,u,s] = (Q[bh,Mtop[u]] · K[bh,s]) / 8.  Block: (bh, s-chunk of 256).
// ---------------------------------------------------------------------------
__global__ __launch_bounds__(256) void scores_kernel(const float* __restrict__ Q,
                                                     const float* __restrict__ K,
                                                     const int* __restrict__ Mtop,
                                                     float* __restrict__ scores) {
  __shared__ float Qs[NT * DH];
  const int bh = blockIdx.x, tid = threadIdx.x;
  for (int i = tid; i < NT * DH; i += 256) {
    int u = i >> 6, dk = i & 63;
    int row = Mtop[bh * NT + u];
    Qs[i] = Q[((size_t)bh * SEQ + row) * DH + dk];
  }
  __syncthreads();
  const int s = blockIdx.y * 256 + tid;
  const float* Krow = K + ((size_t)bh * SEQ + s) * DH;
  float4 kr[16];
#pragma unroll
  for (int g = 0; g < 16; g++) kr[g] = *(const float4*)&Krow[g * 4];
  for (int u = 0; u < NT; u++) {
    float acc = 0.f;
#pragma unroll
    for (int g = 0; g < 16; g++) {
      float4 qv = *(const float4*)&Qs[u * DH + g * 4];
      acc = fmaf(qv.x, kr[g].x, acc);
      acc = fmaf(qv.y, kr[g].y, acc);
      acc = fmaf(qv.z, kr[g].z, acc);
      acc = fmaf(qv.w, kr[g].w, acc);
    }
    scores[((size_t)bh * NT + u) * SEQ + s] = acc * 0.125f;
  }
}

// ---------------------------------------------------------------------------
// Row softmax over 2048, in place. One block per (bh,u) row.
// ---------------------------------------------------------------------------
__global__ __launch_bounds__(256) void softmax_kernel(float* __restrict__ scores) {
  __shared__ float red[256];
  const int row = blockIdx.x, tid = threadIdx.x;
  float* p = scores + (size_t)row * SEQ;
  float4 v0 = *(const float4*)&p[tid * 4];
  float4 v1 = *(const float4*)&p[1024 + tid * 4];
  float mx = fmaxf(fmaxf(fmaxf(v0.x, v0.y), fmaxf(v0.z, v0.w)),
                   fmaxf(fmaxf(v1.x, v1.y), fmaxf(v1.z, v1.w)));
  red[tid] = mx;
  __syncthreads();
  for (int s = 128; s; s >>= 1) {
    if (tid < s) red[tid] = fmaxf(red[tid], red[tid + s]);
    __syncthreads();
  }
  mx = red[0];
  __syncthreads();
  v0.x = __expf(v0.x - mx); v0.y = __expf(v0.y - mx);
  v0.z = __expf(v0.z - mx); v0.w = __expf(v0.w - mx);
  v1.x = __expf(v1.x - mx); v1.y = __expf(v1.y - mx);
  v1.z = __expf(v1.z - mx); v1.w = __expf(v1.w - mx);
  float sm = v0.x + v0.y + v0.z + v0.w + v1.x + v1.y + v1.z + v1.w;
  red[tid] = sm;
  __syncthreads();
  for (int s = 128; s; s >>= 1) {
    if (tid < s) red[tid] += red[tid + s];
    __syncthreads();
  }
  float inv = 1.0f / red[0];
  v0.x *= inv; v0.y *= inv; v0.z *= inv; v0.w *= inv;
  v1.x *= inv; v1.y *= inv; v1.z *= inv; v1.w *= inv;
  *(float4*)&p[tid * 4] = v0;
  *(float4*)&p[1024 + tid * 4] = v1;
}

// ---------------------------------------------------------------------------
// Partial upd = attn @ V over one 256-wide s-chunk. No atomics.
// updp[((bh*NSC+sc)*NT + u)*DH + dk]. Block: (bh, sc). 4 waves, u=wid+4i.
// ---------------------------------------------------------------------------
__global__ __launch_bounds__(256) void pv_partial_kernel(const float* __restrict__ attn,
                                                         const float* __restrict__ V,
                                                         float* __restrict__ updp) {
  __shared__ float Vl[64 * DH];     // [sj][dk]
  __shared__ float Al[NT * 64];     // [u][sj]
  const int bh = blockIdx.x, sc = blockIdx.y, tid = threadIdx.x;
  const int s0 = sc * 256;
  const int wid = tid >> 6, dk = tid & 63;
  float acc[10] = {};

  for (int st = 0; st < 4; st++) {
    const int sb = s0 + st * 64;
    __syncthreads();
#pragma unroll
    for (int i = 0; i < 16; i++) {
      int idx = tid + i * 256;  // 4096
      int sj = idx >> 6, d2 = idx & 63;
      Vl[idx] = V[((size_t)bh * SEQ + sb + sj) * DH + d2];
    }
#pragma unroll
    for (int i = 0; i < 10; i++) {
      int idx = tid + i * 256;  // 2560
      int u = idx >> 6, sj = idx & 63;
      Al[idx] = attn[((size_t)bh * NT + u) * SEQ + sb + sj];
    }
    __syncthreads();
    for (int g = 0; g < 16; g++) {
      float a[10][4];
#pragma unroll
      for (int i = 0; i < 10; i++) {
        float4 t = *(const float4*)&Al[(wid + 4 * i) * 64 + g * 4];  // wave-broadcast
        a[i][0] = t.x; a[i][1] = t.y; a[i][2] = t.z; a[i][3] = t.w;
      }
#pragma unroll
      for (int t = 0; t < 4; t++) {
        float v = Vl[(g * 4 + t) * DH + dk];
#pragma unroll
        for (int i = 0; i < 10; i++) acc[i] = fmaf(a[i][t], v, acc[i]);
      }
    }
  }

#pragma unroll
  for (int i = 0; i < 10; i++) {
    int u = wid + 4 * i;
    updp[((size_t)(bh * NSC + sc) * NT + u) * DH + dk] = acc[i];
  }
}

// ---------------------------------------------------------------------------
// Sum the NSC partials in fixed order, overwrite selected ctxT rows.
// Grid (32 bh, 10); thread (tid>>6 -> u sub, tid&63 -> dk). Deterministic:
// distinct rows per (b,h), distinct head-slices across h.
// ---------------------------------------------------------------------------
__global__ __launch_bounds__(256) void reduce_scatter_kernel(const float* __restrict__ updp,
                                                             const int* __restrict__ Mtop,
                                                             float* __restrict__ ctxT) {
  const int bh = blockIdx.x;
  const int u = blockIdx.y * 4 + (threadIdx.x >> 6);
  const int dk = threadIdx.x & 63;
  float s = 0.f;
#pragma unroll
  for (int sc = 0; sc < NSC; sc++)
    s += updp[((size_t)(bh * NSC + sc) * NT + u) * DH + dk];
  const int row = Mtop[bh * NT + u];
  const int b = bh >> 3, h = bh & 7;
  ctxT[((size_t)b * SEQ + row) * DM + h * DH + dk] = s;
}

// ---------------------------------------------------------------------------
extern "C" void kernel_launch(void* const* d_in, const int* in_sizes, int n_in,
                              void* d_out, int out_size, void* d_ws, size_t ws_size,
                              hipStream_t stream) {
  (void)in_sizes; (void)n_in; (void)out_size; (void)ws_size;
  const float* queries = (const float*)d_in[0];
  const float* keys    = (const float*)d_in[1];
  const float* values  = (const float*)d_in[2];
  // d_in[3] attn_mask: unused by the reference
  const int* index_sample = (const int*)d_in[4];
  const float* Wq = (const float*)d_in[5];
  const float* bq = (const float*)d_in[6];
  const float* Wk = (const float*)d_in[7];
  const float* bk = (const float*)d_in[8];
  const float* Wv = (const float*)d_in[9];
  const float* bv = (const float*)d_in[10];
  const float* Wo = (const float*)d_in[11];
  const float* bo = (const float*)d_in[12];
  float* out = (float*)d_out;

  // workspace carve-up (floats): Q,K,V,ctxT 4x 4,194,304; scores 2,621,440;
  // M 65,536; Vsum 2,048; vpart 32,768; Mtop 1,280 ints  => ~78 MB.
  // updp (655,360 floats) aliases Q, which is dead after scores_kernel.
  float* ws = (float*)d_ws;
  float* Q    = ws;
  float* Kp   = Q + (size_t)ROWS * DM;
  float* Vp   = Kp + (size_t)ROWS * DM;
  float* ctxT = Vp + (size_t)ROWS * DM;
  float* scores = ctxT + (size_t)ROWS * DM;
  float* M    = scores + (size_t)NB * NH * NT * SEQ;
  float* Vsum = M + BHROWS;
  float* vpart = Vsum + NB * NH * DH;
  int* Mtop   = (int*)(vpart + NB * NH * VCH * DH);
  float* updp = Q;  // reuse: Q dead after scores_kernel

  const dim3 gg(ROWS / 128, DM / 64);
  gemm128<true><<<gg, 256, 0, stream>>>(queries, Wq, bq, Q);
  gemm128<true><<<gg, 256, 0, stream>>>(keys, Wk, bk, Kp);
  gemm128<true><<<gg, 256, 0, stream>>>(values, Wv, bv, Vp);
  m_kernel<<<BHROWS / 4, 256, 0, stream>>>(Q, Kp, index_sample, M);
  topk_kernel<<<NB * NH, 256, 0, stream>>>(M, Mtop);
  vsum1_kernel<<<dim3(NB * NH, VCH), 256, 0, stream>>>(Vp, vpart);
  vsum2_kernel<<<NB * NH, 64, 0, stream>>>(vpart, Vsum);
  ctxinit_kernel<<<(ROWS * DM / 4) / 256, 256, 0, stream>>>(Vsum, ctxT);
  scores_kernel<<<dim3(NB * NH, SEQ / 256), 256, 0, stream>>>(Q, Kp, Mtop, scores);
  softmax_kernel<<<NB * NH * NT, 256, 0, stream>>>(scores);
  pv_partial_kernel<<<dim3(NB * NH, NSC), 256, 0, stream>>>(scores, Vp, updp);
  reduce_scatter_kernel<<<dim3(NB * NH, NT / 4), 256, 0, stream>>>(updp, Mtop, ctxT);
  gemm128<false><<<gg, 256, 0, stream>>>(ctxT, Wo, bo, out);
}

// Round 5
// 258.107 us; speedup vs baseline: 2.5152x; 1.4779x over previous
//
#include <hip/hip_runtime.h>

// ProbSparse attention (Informer) — B=4, L=2048, D=512, H=8, DK=64, SK=NTOP=40
// Round 5: MFMA GEMMs. Q/K projections = split-bf16 3-pass (top-k selection
// needs ~fp32 accuracy); V/out projections = single-pass bf16.

typedef unsigned short u16;
typedef __attribute__((ext_vector_type(8))) short short8;
typedef __attribute__((ext_vector_type(4))) float f32x4;

constexpr int NB = 4;       // batch
constexpr int SEQ = 2048;   // L
constexpr int DM = 512;     // D
constexpr int NH = 8;
constexpr int DH = 64;      // DK
constexpr int NS = 40;      // SK (samples)
constexpr int NT = 40;      // NTOP
constexpr int ROWS = NB * SEQ;          // 8192
constexpr int BHROWS = NB * NH * SEQ;   // 65536
constexpr int NSC = 8;      // s-chunks in pv (SEQ/256)
constexpr int VCH = 16;     // vsum l-chunks per (b,h)

// ---------------------------------------------------------------------------
// bf16 helpers (round-to-nearest-even)
// ---------------------------------------------------------------------------
__device__ __forceinline__ u16 f2bf(float x) {
  union { float f; unsigned u; } v; v.f = x;
  unsigned r = v.u + 0x7FFFu + ((v.u >> 16) & 1u);
  return (u16)(r >> 16);
}
__device__ __forceinline__ float bf2f(u16 b) {
  union { unsigned u; float f; } v; v.u = ((unsigned)b) << 16;
  return v.f;
}

__device__ __forceinline__ void gload16(void* lds, const void* g) {
  __builtin_amdgcn_global_load_lds(
      (const __attribute__((address_space(1))) unsigned int*)g,
      (__attribute__((address_space(3))) unsigned int*)lds, 16, 0, 0);
}

// ---------------------------------------------------------------------------
// X (R x 512 fp32, row-major) -> H (+L) bf16, same layout. One float4/thread.
// ---------------------------------------------------------------------------
__global__ __launch_bounds__(256) void cvt_split_kernel(const float* __restrict__ X,
                                                        u16* __restrict__ H,
                                                        u16* __restrict__ L,
                                                        int doLo) {
  const int i = blockIdx.x * 256 + threadIdx.x;
  float4 v = ((const float4*)X)[i];
  ushort4 h;
  h.x = f2bf(v.x); h.y = f2bf(v.y); h.z = f2bf(v.z); h.w = f2bf(v.w);
  ((ushort4*)H)[i] = h;
  if (doLo) {
    ushort4 l;
    l.x = f2bf(v.x - bf2f(h.x)); l.y = f2bf(v.y - bf2f(h.y));
    l.z = f2bf(v.z - bf2f(h.z)); l.w = f2bf(v.w - bf2f(h.w));
    ((ushort4*)L)[i] = l;
  }
}

// ---------------------------------------------------------------------------
// W (512x512 fp32, [k][n]) -> Wt bf16 [n][k] hi (+lo). 64x64 tiles, grid (8,8).
// ---------------------------------------------------------------------------
__global__ __launch_bounds__(256) void cvt_wt_kernel(const float* __restrict__ W,
                                                     u16* __restrict__ H,
                                                     u16* __restrict__ L,
                                                     int doLo) {
  __shared__ float T[64][65];
  const int c0 = blockIdx.x * 64;  // n
  const int r0 = blockIdx.y * 64;  // k
  const int t = threadIdx.x;
  const int lr = t >> 4, lc4 = (t & 15) * 4;
#pragma unroll
  for (int i = 0; i < 4; i++) {
    float4 v = *(const float4*)&W[(size_t)(r0 + lr + i * 16) * DM + c0 + lc4];
    T[lr + i * 16][lc4 + 0] = v.x;
    T[lr + i * 16][lc4 + 1] = v.y;
    T[lr + i * 16][lc4 + 2] = v.z;
    T[lr + i * 16][lc4 + 3] = v.w;
  }
  __syncthreads();
#pragma unroll
  for (int i = 0; i < 4; i++) {
    const int n = lr + i * 16;
    float x0 = T[lc4 + 0][n], x1 = T[lc4 + 1][n], x2 = T[lc4 + 2][n], x3 = T[lc4 + 3][n];
    ushort4 h;
    h.x = f2bf(x0); h.y = f2bf(x1); h.z = f2bf(x2); h.w = f2bf(x3);
    *(ushort4*)&H[(size_t)(c0 + n) * DM + r0 + lc4] = h;
    if (doLo) {
      ushort4 l;
      l.x = f2bf(x0 - bf2f(h.x)); l.y = f2bf(x1 - bf2f(h.y));
      l.z = f2bf(x2 - bf2f(h.z)); l.w = f2bf(x3 - bf2f(h.w));
      *(ushort4*)&L[(size_t)(c0 + n) * DM + r0 + lc4] = l;
    }
  }
}

// ---------------------------------------------------------------------------
// MFMA GEMM: C(8192x512) = X(8192x512) @ W(512x512) + bias, bf16 inputs.
// X as [M][K] bf16 (hi/lo); W pre-transposed [N][K] bf16 (hi/lo).
// 128(M) x 64(N) tile, BK=32, 256 thr, 4 waves (2x2), wave tile 64x32.
// SPLIT3: 3-pass split-bf16 (Ah*Bh + Ah*Bl + Al*Bh). TOSPLIT: (B,H,L,DH) out.
// ---------------------------------------------------------------------------
template <bool SPLIT3, bool TOSPLIT>
__global__ __launch_bounds__(256) void gemm_mfma(const u16* __restrict__ XH,
                                                 const u16* __restrict__ XL,
                                                 const u16* __restrict__ WTH,
                                                 const u16* __restrict__ WTL,
                                                 const float* __restrict__ bias,
                                                 float* __restrict__ out) {
  __shared__ __align__(16) u16 Ah[128 * 32];
  __shared__ __align__(16) u16 Al[128 * 32];
  __shared__ __align__(16) u16 Bh[64 * 32];
  __shared__ __align__(16) u16 Bl[64 * 32];
  const int tid = threadIdx.x, lane = tid & 63, w = tid >> 6;
  const int row0 = blockIdx.x * 128, col0 = blockIdx.y * 64;
  const int wr = (w >> 1) * 64, wc = (w & 1) * 32;
  const int lr = lane & 15, kb8 = (lane >> 4) * 8;
  const int mrow = lane >> 2;          // row within 16-row chunk
  const int kcol = (lane & 3) * 8;     // bf16 elements into the 32-wide k slab

  f32x4 acc[4][2];
#pragma unroll
  for (int i = 0; i < 4; i++)
#pragma unroll
    for (int j = 0; j < 2; j++) acc[i][j] = (f32x4){0.f, 0.f, 0.f, 0.f};

  constexpr int PER = SPLIT3 ? 6 : 3;  // staging chunks per wave

  for (int k0 = 0; k0 < DM; k0 += 32) {
    __syncthreads();
#pragma unroll
    for (int i = 0; i < PER; i++) {
      const int c = w * PER + i;
      const u16* g;
      u16* l;
      if (SPLIT3) {
        if (c < 8)       { g = XH  + (size_t)(row0 + c * 16 + mrow) * DM + k0 + kcol;        l = Ah + c * 512; }
        else if (c < 16) { g = XL  + (size_t)(row0 + (c - 8) * 16 + mrow) * DM + k0 + kcol;  l = Al + (c - 8) * 512; }
        else if (c < 20) { g = WTH + (size_t)(col0 + (c - 16) * 16 + mrow) * DM + k0 + kcol; l = Bh + (c - 16) * 512; }
        else             { g = WTL + (size_t)(col0 + (c - 20) * 16 + mrow) * DM + k0 + kcol; l = Bl + (c - 20) * 512; }
      } else {
        if (c < 8)       { g = XH  + (size_t)(row0 + c * 16 + mrow) * DM + k0 + kcol;        l = Ah + c * 512; }
        else             { g = WTH + (size_t)(col0 + (c - 8) * 16 + mrow) * DM + k0 + kcol;  l = Bh + (c - 8) * 512; }
      }
      gload16(l, g);
    }
    __syncthreads();

    short8 ah[4], bh[2];
#pragma unroll
    for (int i = 0; i < 4; i++) ah[i] = *(const short8*)&Ah[(wr + i * 16 + lr) * 32 + kb8];
#pragma unroll
    for (int j = 0; j < 2; j++) bh[j] = *(const short8*)&Bh[(wc + j * 16 + lr) * 32 + kb8];
    if constexpr (SPLIT3) {
      short8 al[4], bl[2];
#pragma unroll
      for (int i = 0; i < 4; i++) al[i] = *(const short8*)&Al[(wr + i * 16 + lr) * 32 + kb8];
#pragma unroll
      for (int j = 0; j < 2; j++) bl[j] = *(const short8*)&Bl[(wc + j * 16 + lr) * 32 + kb8];
#pragma unroll
      for (int i = 0; i < 4; i++)
#pragma unroll
        for (int j = 0; j < 2; j++) {
          acc[i][j] = __builtin_amdgcn_mfma_f32_16x16x32_bf16(ah[i], bh[j], acc[i][j], 0, 0, 0);
          acc[i][j] = __builtin_amdgcn_mfma_f32_16x16x32_bf16(ah[i], bl[j], acc[i][j], 0, 0, 0);
          acc[i][j] = __builtin_amdgcn_mfma_f32_16x16x32_bf16(al[i], bh[j], acc[i][j], 0, 0, 0);
        }
    } else {
#pragma unroll
      for (int i = 0; i < 4; i++)
#pragma unroll
        for (int j = 0; j < 2; j++)
          acc[i][j] = __builtin_amdgcn_mfma_f32_16x16x32_bf16(ah[i], bh[j], acc[i][j], 0, 0, 0);
    }
  }

  // epilogue: D layout col=lane&15, row=(lane>>4)*4+r
#pragma unroll
  for (int i = 0; i < 4; i++)
#pragma unroll
    for (int j = 0; j < 2; j++) {
      const int col = col0 + wc + j * 16 + lr;
      const float bval = bias[col];
#pragma unroll
      for (int r = 0; r < 4; r++) {
        const int row = row0 + wr + i * 16 + (lane >> 4) * 4 + r;
        const float v = acc[i][j][r] + bval;
        if constexpr (TOSPLIT) {
          const int b = row >> 11, l2 = row & (SEQ - 1);
          const int h = col >> 6, dk = col & 63;
          out[((size_t)(b * NH + h) * SEQ + l2) * DH + dk] = v;
        } else {
          out[(size_t)row * DM + col] = v;
        }
      }
    }
}

// ---------------------------------------------------------------------------
// M[b,h,q] = max_j(Q[bhq]·K[bh,idx[q,j]]) - sum_j(...)/SEQ.  One wave per row.
// ---------------------------------------------------------------------------
__global__ __launch_bounds__(256) void m_kernel(const float* __restrict__ Q,
                                                const float* __restrict__ K,
                                                const int* __restrict__ idxs,
                                                float* __restrict__ M) {
  const int lane = threadIdx.x & 63;
  const int r = blockIdx.x * 4 + (threadIdx.x >> 6);  // [0, BHROWS)
  const int q = r & (SEQ - 1);
  const int g = lane >> 3;        // sample group 0..7
  const int d8 = (lane & 7) * 8;  // dim slice start
  const float* Qr = Q + (size_t)r * DH + d8;
  const float4 q0 = *(const float4*)Qr;
  const float4 q1 = *(const float4*)(Qr + 4);
  const float* Kbh = K + (size_t)(r >> 11) * SEQ * DH;

  int ks[5];
#pragma unroll
  for (int p = 0; p < 5; p++) ks[p] = idxs[q * NS + g + 8 * p];
  float4 k0[5], k1[5];
#pragma unroll
  for (int p = 0; p < 5; p++) {
    const float* Kr = Kbh + (size_t)ks[p] * DH + d8;
    k0[p] = *(const float4*)Kr;
    k1[p] = *(const float4*)(Kr + 4);
  }
  float mx = -1e30f, sm = 0.f;
#pragma unroll
  for (int p = 0; p < 5; p++) {
    float acc = q0.x * k0[p].x + q0.y * k0[p].y + q0.z * k0[p].z + q0.w * k0[p].w +
                q1.x * k1[p].x + q1.y * k1[p].y + q1.z * k1[p].z + q1.w * k1[p].w;
    acc += __shfl_xor(acc, 1, 64);
    acc += __shfl_xor(acc, 2, 64);
    acc += __shfl_xor(acc, 4, 64);
    mx = fmaxf(mx, acc);
    sm += acc;
  }
#pragma unroll
  for (int o = 8; o <= 32; o <<= 1) {
    mx = fmaxf(mx, __shfl_xor(mx, o, 64));
    sm += __shfl_xor(sm, o, 64);
  }
  if (lane == 0) M[r] = mx - sm * (1.0f / (float)SEQ);
}

// ---------------------------------------------------------------------------
// Top-40 of M per (b,h). Tie-break: lower index (matches jax top_k).
// ---------------------------------------------------------------------------
__global__ __launch_bounds__(256) void topk_kernel(const float* __restrict__ M,
                                                   int* __restrict__ Mtop) {
  __shared__ float vals[SEQ];
  __shared__ float wv[4];
  __shared__ int wi[4];
  const int bh = blockIdx.x, tid = threadIdx.x;
  const int lane = tid & 63, wid = tid >> 6;
  for (int i = tid; i < SEQ; i += 256) vals[i] = M[bh * SEQ + i];
  __syncthreads();
  for (int it = 0; it < NT; it++) {
    float bm = -1e30f;
    int bi = 0x7fffffff;
    for (int i = tid; i < SEQ; i += 256) {
      float v = vals[i];
      if (v > bm) { bm = v; bi = i; }
    }
#pragma unroll
    for (int o = 1; o <= 32; o <<= 1) {
      float ov = __shfl_xor(bm, o, 64);
      int oi = __shfl_xor(bi, o, 64);
      if (ov > bm || (ov == bm && oi < bi)) { bm = ov; bi = oi; }
    }
    if (lane == 0) { wv[wid] = bm; wi[wid] = bi; }
    __syncthreads();
    if (tid == 0) {
      float fm = wv[0];
      int fi = wi[0];
#pragma unroll
      for (int w = 1; w < 4; w++) {
        if (wv[w] > fm || (wv[w] == fm && wi[w] < fi)) { fm = wv[w]; fi = wi[w]; }
      }
      Mtop[bh * NT + it] = fi;
      vals[fi] = -1e30f;
    }
    __syncthreads();
  }
}

// ---------------------------------------------------------------------------
// V_sum stage 1: partial[bh][c][dk] = sum of 128 rows. Grid (32, 16).
// ---------------------------------------------------------------------------
__global__ __launch_bounds__(256) void vsum1_kernel(const float* __restrict__ V,
                                                    float* __restrict__ part) {
  __shared__ float sm[4][DH];
  const int bh = blockIdx.x, c = blockIdx.y, tid = threadIdx.x;
  const int dk = tid & 63, p = tid >> 6;
  const float* Vb = V + ((size_t)bh * SEQ + c * (SEQ / VCH)) * DH;
  float s = 0.f;
  for (int l = p; l < SEQ / VCH; l += 4) s += Vb[(size_t)l * DH + dk];
  sm[p][dk] = s;
  __syncthreads();
  if (p == 0)
    part[(size_t)(bh * VCH + c) * DH + dk] = sm[0][dk] + sm[1][dk] + sm[2][dk] + sm[3][dk];
}

__global__ __launch_bounds__(64) void vsum2_kernel(const float* __restrict__ part,
                                                   float* __restrict__ Vsum) {
  const int bh = blockIdx.x, dk = threadIdx.x;
  float s = 0.f;
#pragma unroll
  for (int c = 0; c < VCH; c++) s += part[(size_t)(bh * VCH + c) * DH + dk];
  Vsum[bh * DH + dk] = s;
}

// ---------------------------------------------------------------------------
// ctxT (B,L,D): V_sum broadcast (selected rows overwritten by reduce_scatter).
// ---------------------------------------------------------------------------
__global__ __launch_bounds__(256) void ctxinit_kernel(const float* __restrict__ Vsum,
                                                      float* __restrict__ ctxT) {
  const int idx = blockIdx.x * 256 + threadIdx.x;  // float4 index
  const int f = idx * 4;
  const int d = f & (DM - 1), b = f >> 20;
  float4 v = *(const float4*)&Vsum[b * DM + d];
  *(float4*)&ctxT[f] = v;
}

// ---------------------------------------------------------------------------
// scores[bh,u,s] = (Q[bh,Mtop[u]] · K[bh,s]) / 8.  Block: (bh, s-chunk of 256).
// ---------------------------------------------------------------------------
__global__ __launch_bounds__(256) void scores_kernel(const float* __restrict__ Q,
                                                     const float* __restrict__ K,
                                                     const int* __restrict__ Mtop,
                                                     float* __restrict__ scores) {
  __shared__ float Qs[NT * DH];
  const int bh = blockIdx.x, tid = threadIdx.x;
  for (int i = tid; i < NT * DH; i += 256) {
    int u = i >> 6, dk = i & 63;
    int row = Mtop[bh * NT + u];
    Qs[i] = Q[((size_t)bh * SEQ + row) * DH + dk];
  }
  __syncthreads();
  const int s = blockIdx.y * 256 + tid;
  const float* Krow = K + ((size_t)bh * SEQ + s) * DH;
  float4 kr[16];
#pragma unroll
  for (int g = 0; g < 16; g++) kr[g] = *(const float4*)&Krow[g * 4];
  for (int u = 0; u < NT; u++) {
    float acc = 0.f;
#pragma unroll
    for (int g = 0; g < 16; g++) {
      float4 qv = *(const float4*)&Qs[u * DH + g * 4];
      acc = fmaf(qv.x, kr[g].x, acc);
      acc = fmaf(qv.y, kr[g].y, acc);
      acc = fmaf(qv.z, kr[g].z, acc);
      acc = fmaf(qv.w, kr[g].w, acc);
    }
    scores[((size_t)bh * NT + u) * SEQ + s] = acc * 0.125f;
  }
}

// ---------------------------------------------------------------------------
// Row softmax over 2048, in place. One block per (bh,u) row.
// ---------------------------------------------------------------------------
__global__ __launch_bounds__(256) void softmax_kernel(float* __restrict__ scores) {
  __shared__ float red[256];
  const int row = blockIdx.x, tid = threadIdx.x;
  float* p = scores + (size_t)row * SEQ;
  float4 v0 = *(const float4*)&p[tid * 4];
  float4 v1 = *(const float4*)&p[1024 + tid * 4];
  float mx = fmaxf(fmaxf(fmaxf(v0.x, v0.y), fmaxf(v0.z, v0.w)),
                   fmaxf(fmaxf(v1.x, v1.y), fmaxf(v1.z, v1.w)));
  red[tid] = mx;
  __syncthreads();
  for (int s = 128; s; s >>= 1) {
    if (tid < s) red[tid] = fmaxf(red[tid], red[tid + s]);
    __syncthreads();
  }
  mx = red[0];
  __syncthreads();
  v0.x = __expf(v0.x - mx); v0.y = __expf(v0.y - mx);
  v0.z = __expf(v0.z - mx); v0.w = __expf(v0.w - mx);
  v1.x = __expf(v1.x - mx); v1.y = __expf(v1.y - mx);
  v1.z = __expf(v1.z - mx); v1.w = __expf(v1.w - mx);
  float sm = v0.x + v0.y + v0.z + v0.w + v1.x + v1.y + v1.z + v1.w;
  red[tid] = sm;
  __syncthreads();
  for (int s = 128; s; s >>= 1) {
    if (tid < s) red[tid] += red[tid + s];
    __syncthreads();
  }
  float inv = 1.0f / red[0];
  v0.x *= inv; v0.y *= inv; v0.z *= inv; v0.w *= inv;
  v1.x *= inv; v1.y *= inv; v1.z *= inv; v1.w *= inv;
  *(float4*)&p[tid * 4] = v0;
  *(float4*)&p[1024 + tid * 4] = v1;
}

// ---------------------------------------------------------------------------
// Partial upd = attn @ V over one 256-wide s-chunk. No atomics.
// ---------------------------------------------------------------------------
__global__ __launch_bounds__(256) void pv_partial_kernel(const float* __restrict__ attn,
                                                         const float* __restrict__ V,
                                                         float* __restrict__ updp) {
  __shared__ float Vl[64 * DH];
  __shared__ float Al2[NT * 64];
  const int bh = blockIdx.x, sc = blockIdx.y, tid = threadIdx.x;
  const int s0 = sc * 256;
  const int wid = tid >> 6, dk = tid & 63;
  float acc[10] = {};

  for (int st = 0; st < 4; st++) {
    const int sb = s0 + st * 64;
    __syncthreads();
#pragma unroll
    for (int i = 0; i < 16; i++) {
      int idx = tid + i * 256;
      int sj = idx >> 6, d2 = idx & 63;
      Vl[idx] = V[((size_t)bh * SEQ + sb + sj) * DH + d2];
    }
#pragma unroll
    for (int i = 0; i < 10; i++) {
      int idx = tid + i * 256;
      int u = idx >> 6, sj = idx & 63;
      Al2[idx] = attn[((size_t)bh * NT + u) * SEQ + sb + sj];
    }
    __syncthreads();
    for (int g = 0; g < 16; g++) {
      float a[10][4];
#pragma unroll
      for (int i = 0; i < 10; i++) {
        float4 t = *(const float4*)&Al2[(wid + 4 * i) * 64 + g * 4];
        a[i][0] = t.x; a[i][1] = t.y; a[i][2] = t.z; a[i][3] = t.w;
      }
#pragma unroll
      for (int t = 0; t < 4; t++) {
        float v = Vl[(g * 4 + t) * DH + dk];
#pragma unroll
        for (int i = 0; i < 10; i++) acc[i] = fmaf(a[i][t], v, acc[i]);
      }
    }
  }

#pragma unroll
  for (int i = 0; i < 10; i++) {
    int u = wid + 4 * i;
    updp[((size_t)(bh * NSC + sc) * NT + u) * DH + dk] = acc[i];
  }
}

// ---------------------------------------------------------------------------
// Sum the NSC partials in fixed order, overwrite selected ctxT rows.
// ---------------------------------------------------------------------------
__global__ __launch_bounds__(256) void reduce_scatter_kernel(const float* __restrict__ updp,
                                                             const int* __restrict__ Mtop,
                                                             float* __restrict__ ctxT) {
  const int bh = blockIdx.x;
  const int u = blockIdx.y * 4 + (threadIdx.x >> 6);
  const int dk = threadIdx.x & 63;
  float s = 0.f;
#pragma unroll
  for (int sc = 0; sc < NSC; sc++)
    s += updp[((size_t)(bh * NSC + sc) * NT + u) * DH + dk];
  const int row = Mtop[bh * NT + u];
  const int b = bh >> 3, h = bh & 7;
  ctxT[((size_t)b * SEQ + row) * DM + h * DH + dk] = s;
}

// ---------------------------------------------------------------------------
extern "C" void kernel_launch(void* const* d_in, const int* in_sizes, int n_in,
                              void* d_out, int out_size, void* d_ws, size_t ws_size,
                              hipStream_t stream) {
  (void)in_sizes; (void)n_in; (void)out_size; (void)ws_size;
  const float* queries = (const float*)d_in[0];
  const float* keys    = (const float*)d_in[1];
  const float* values  = (const float*)d_in[2];
  const int* index_sample = (const int*)d_in[4];
  const float* Wq = (const float*)d_in[5];
  const float* bq = (const float*)d_in[6];
  const float* Wk = (const float*)d_in[7];
  const float* bk = (const float*)d_in[8];
  const float* Wv = (const float*)d_in[9];
  const float* bv = (const float*)d_in[10];
  const float* Wo = (const float*)d_in[11];
  const float* bo = (const float*)d_in[12];
  float* out = (float*)d_out;

  // ws (floats): Q,Kp,Vp,ctxT 4x 4,194,304; scores 2,621,440; M 65,536;
  // Vsum 2,048; vpart 32,768; Mtop ints  => ~78 MB (same as round 4).
  // bf16 staging aliases dead regions:
  //   XH/XL -> ctxT region (dead until ctxinit)
  //   WH/WL -> scores region (dead until scores_kernel)
  //   CH/WoH -> scores region (dead after pv_partial)
  //   updp  -> Q region (dead after scores_kernel)
  float* ws = (float*)d_ws;
  float* Q    = ws;
  float* Kp   = Q + (size_t)ROWS * DM;
  float* Vp   = Kp + (size_t)ROWS * DM;
  float* ctxT = Vp + (size_t)ROWS * DM;
  float* scores = ctxT + (size_t)ROWS * DM;
  float* M    = scores + (size_t)NB * NH * NT * SEQ;
  float* Vsum = M + BHROWS;
  float* vpart = Vsum + NB * NH * DH;
  int* Mtop   = (int*)(vpart + NB * NH * VCH * DH);
  float* updp = Q;

  u16* XH = (u16*)ctxT;
  u16* XL = XH + (size_t)ROWS * DM;
  u16* WH = (u16*)scores;
  u16* WL = WH + (size_t)DM * DM;
  u16* CH  = (u16*)scores;
  u16* WoH = CH + (size_t)ROWS * DM;

  const int n4x = ROWS * DM / 4;          // 1,048,576 float4s
  const dim3 gG(ROWS / 128, DM / 64);     // (64, 8)
  const dim3 gW(8, 8);

  // Q projection (split-bf16 3-pass)
  cvt_split_kernel<<<n4x / 256, 256, 0, stream>>>(queries, XH, XL, 1);
  cvt_wt_kernel<<<gW, 256, 0, stream>>>(Wq, WH, WL, 1);
  gemm_mfma<true, true><<<gG, 256, 0, stream>>>(XH, XL, WH, WL, bq, Q);
  // K projection (split-bf16 3-pass)
  cvt_split_kernel<<<n4x / 256, 256, 0, stream>>>(keys, XH, XL, 1);
  cvt_wt_kernel<<<gW, 256, 0, stream>>>(Wk, WH, WL, 1);
  gemm_mfma<true, true><<<gG, 256, 0, stream>>>(XH, XL, WH, WL, bk, Kp);
  // V projection (single-pass bf16)
  cvt_split_kernel<<<n4x / 256, 256, 0, stream>>>(values, XH, XL, 0);
  cvt_wt_kernel<<<gW, 256, 0, stream>>>(Wv, WH, WL, 0);
  gemm_mfma<false, true><<<gG, 256, 0, stream>>>(XH, XH, WH, WH, bv, Vp);

  m_kernel<<<BHROWS / 4, 256, 0, stream>>>(Q, Kp, index_sample, M);
  topk_kernel<<<NB * NH, 256, 0, stream>>>(M, Mtop);
  vsum1_kernel<<<dim3(NB * NH, VCH), 256, 0, stream>>>(Vp, vpart);
  vsum2_kernel<<<NB * NH, 64, 0, stream>>>(vpart, Vsum);
  ctxinit_kernel<<<(ROWS * DM / 4) / 256, 256, 0, stream>>>(Vsum, ctxT);
  scores_kernel<<<dim3(NB * NH, SEQ / 256), 256, 0, stream>>>(Q, Kp, Mtop, scores);
  softmax_kernel<<<NB * NH * NT, 256, 0, stream>>>(scores);
  pv_partial_kernel<<<dim3(NB * NH, NSC), 256, 0, stream>>>(scores, Vp, updp);
  reduce_scatter_kernel<<<dim3(NB * NH, NT / 4), 256, 0, stream>>>(updp, Mtop, ctxT);

  // Output projection (single-pass bf16)
  cvt_split_kernel<<<n4x / 256, 256, 0, stream>>>(ctxT, CH, CH, 0);
  cvt_wt_kernel<<<gW, 256, 0, stream>>>(Wo, WoH, WoH, 0);
  gemm_mfma<false, false><<<gG, 256, 0, stream>>>(CH, CH, WoH, WoH, bo, out);
}

// Round 6
// 256.929 us; speedup vs baseline: 2.5268x; 1.0046x over previous
//
#include <hip/hip_runtime.h>

// ProbSparse attention (Informer) — B=4, L=2048, D=512, H=8, DK=64, SK=NTOP=40
// Round 6: register-resident single-wave top-k (R5 topk was 44.5us, 40 serial
// block-wide iterations). Everything else unchanged from R5.

typedef unsigned short u16;
typedef __attribute__((ext_vector_type(8))) short short8;
typedef __attribute__((ext_vector_type(4))) float f32x4;

constexpr int NB = 4;       // batch
constexpr int SEQ = 2048;   // L
constexpr int DM = 512;     // D
constexpr int NH = 8;
constexpr int DH = 64;      // DK
constexpr int NS = 40;      // SK (samples)
constexpr int NT = 40;      // NTOP
constexpr int ROWS = NB * SEQ;          // 8192
constexpr int BHROWS = NB * NH * SEQ;   // 65536
constexpr int NSC = 8;      // s-chunks in pv (SEQ/256)
constexpr int VCH = 16;     // vsum l-chunks per (b,h)

// ---------------------------------------------------------------------------
// bf16 helpers (round-to-nearest-even)
// ---------------------------------------------------------------------------
__device__ __forceinline__ u16 f2bf(float x) {
  union { float f; unsigned u; } v; v.f = x;
  unsigned r = v.u + 0x7FFFu + ((v.u >> 16) & 1u);
  return (u16)(r >> 16);
}
__device__ __forceinline__ float bf2f(u16 b) {
  union { unsigned u; float f; } v; v.u = ((unsigned)b) << 16;
  return v.f;
}

__device__ __forceinline__ void gload16(void* lds, const void* g) {
  __builtin_amdgcn_global_load_lds(
      (const __attribute__((address_space(1))) unsigned int*)g,
      (__attribute__((address_space(3))) unsigned int*)lds, 16, 0, 0);
}

// ---------------------------------------------------------------------------
// X (R x 512 fp32, row-major) -> H (+L) bf16, same layout. One float4/thread.
// ---------------------------------------------------------------------------
__global__ __launch_bounds__(256) void cvt_split_kernel(const float* __restrict__ X,
                                                        u16* __restrict__ H,
                                                        u16* __restrict__ L,
                                                        int doLo) {
  const int i = blockIdx.x * 256 + threadIdx.x;
  float4 v = ((const float4*)X)[i];
  ushort4 h;
  h.x = f2bf(v.x); h.y = f2bf(v.y); h.z = f2bf(v.z); h.w = f2bf(v.w);
  ((ushort4*)H)[i] = h;
  if (doLo) {
    ushort4 l;
    l.x = f2bf(v.x - bf2f(h.x)); l.y = f2bf(v.y - bf2f(h.y));
    l.z = f2bf(v.z - bf2f(h.z)); l.w = f2bf(v.w - bf2f(h.w));
    ((ushort4*)L)[i] = l;
  }
}

// ---------------------------------------------------------------------------
// W (512x512 fp32, [k][n]) -> Wt bf16 [n][k] hi (+lo). 64x64 tiles, grid (8,8).
// ---------------------------------------------------------------------------
__global__ __launch_bounds__(256) void cvt_wt_kernel(const float* __restrict__ W,
                                                     u16* __restrict__ H,
                                                     u16* __restrict__ L,
                                                     int doLo) {
  __shared__ float T[64][65];
  const int c0 = blockIdx.x * 64;  // n
  const int r0 = blockIdx.y * 64;  // k
  const int t = threadIdx.x;
  const int lr = t >> 4, lc4 = (t & 15) * 4;
#pragma unroll
  for (int i = 0; i < 4; i++) {
    float4 v = *(const float4*)&W[(size_t)(r0 + lr + i * 16) * DM + c0 + lc4];
    T[lr + i * 16][lc4 + 0] = v.x;
    T[lr + i * 16][lc4 + 1] = v.y;
    T[lr + i * 16][lc4 + 2] = v.z;
    T[lr + i * 16][lc4 + 3] = v.w;
  }
  __syncthreads();
#pragma unroll
  for (int i = 0; i < 4; i++) {
    const int n = lr + i * 16;
    float x0 = T[lc4 + 0][n], x1 = T[lc4 + 1][n], x2 = T[lc4 + 2][n], x3 = T[lc4 + 3][n];
    ushort4 h;
    h.x = f2bf(x0); h.y = f2bf(x1); h.z = f2bf(x2); h.w = f2bf(x3);
    *(ushort4*)&H[(size_t)(c0 + n) * DM + r0 + lc4] = h;
    if (doLo) {
      ushort4 l;
      l.x = f2bf(x0 - bf2f(h.x)); l.y = f2bf(x1 - bf2f(h.y));
      l.z = f2bf(x2 - bf2f(h.z)); l.w = f2bf(x3 - bf2f(h.w));
      *(ushort4*)&L[(size_t)(c0 + n) * DM + r0 + lc4] = l;
    }
  }
}

// ---------------------------------------------------------------------------
// MFMA GEMM: C(8192x512) = X(8192x512) @ W(512x512) + bias, bf16 inputs.
// X as [M][K] bf16 (hi/lo); W pre-transposed [N][K] bf16 (hi/lo).
// 128(M) x 64(N) tile, BK=32, 256 thr, 4 waves (2x2), wave tile 64x32.
// SPLIT3: 3-pass split-bf16 (Ah*Bh + Ah*Bl + Al*Bh). TOSPLIT: (B,H,L,DH) out.
// ---------------------------------------------------------------------------
template <bool SPLIT3, bool TOSPLIT>
__global__ __launch_bounds__(256) void gemm_mfma(const u16* __restrict__ XH,
                                                 const u16* __restrict__ XL,
                                                 const u16* __restrict__ WTH,
                                                 const u16* __restrict__ WTL,
                                                 const float* __restrict__ bias,
                                                 float* __restrict__ out) {
  __shared__ __align__(16) u16 Ah[128 * 32];
  __shared__ __align__(16) u16 Al[128 * 32];
  __shared__ __align__(16) u16 Bh[64 * 32];
  __shared__ __align__(16) u16 Bl[64 * 32];
  const int tid = threadIdx.x, lane = tid & 63, w = tid >> 6;
  const int row0 = blockIdx.x * 128, col0 = blockIdx.y * 64;
  const int wr = (w >> 1) * 64, wc = (w & 1) * 32;
  const int lr = lane & 15, kb8 = (lane >> 4) * 8;
  const int mrow = lane >> 2;          // row within 16-row chunk
  const int kcol = (lane & 3) * 8;     // bf16 elements into the 32-wide k slab

  f32x4 acc[4][2];
#pragma unroll
  for (int i = 0; i < 4; i++)
#pragma unroll
    for (int j = 0; j < 2; j++) acc[i][j] = (f32x4){0.f, 0.f, 0.f, 0.f};

  constexpr int PER = SPLIT3 ? 6 : 3;  // staging chunks per wave

  for (int k0 = 0; k0 < DM; k0 += 32) {
    __syncthreads();
#pragma unroll
    for (int i = 0; i < PER; i++) {
      const int c = w * PER + i;
      const u16* g;
      u16* l;
      if (SPLIT3) {
        if (c < 8)       { g = XH  + (size_t)(row0 + c * 16 + mrow) * DM + k0 + kcol;        l = Ah + c * 512; }
        else if (c < 16) { g = XL  + (size_t)(row0 + (c - 8) * 16 + mrow) * DM + k0 + kcol;  l = Al + (c - 8) * 512; }
        else if (c < 20) { g = WTH + (size_t)(col0 + (c - 16) * 16 + mrow) * DM + k0 + kcol; l = Bh + (c - 16) * 512; }
        else             { g = WTL + (size_t)(col0 + (c - 20) * 16 + mrow) * DM + k0 + kcol; l = Bl + (c - 20) * 512; }
      } else {
        if (c < 8)       { g = XH  + (size_t)(row0 + c * 16 + mrow) * DM + k0 + kcol;        l = Ah + c * 512; }
        else             { g = WTH + (size_t)(col0 + (c - 8) * 16 + mrow) * DM + k0 + kcol;  l = Bh + (c - 8) * 512; }
      }
      gload16(l, g);
    }
    __syncthreads();

    short8 ah[4], bh[2];
#pragma unroll
    for (int i = 0; i < 4; i++) ah[i] = *(const short8*)&Ah[(wr + i * 16 + lr) * 32 + kb8];
#pragma unroll
    for (int j = 0; j < 2; j++) bh[j] = *(const short8*)&Bh[(wc + j * 16 + lr) * 32 + kb8];
    if constexpr (SPLIT3) {
      short8 al[4], bl[2];
#pragma unroll
      for (int i = 0; i < 4; i++) al[i] = *(const short8*)&Al[(wr + i * 16 + lr) * 32 + kb8];
#pragma unroll
      for (int j = 0; j < 2; j++) bl[j] = *(const short8*)&Bl[(wc + j * 16 + lr) * 32 + kb8];
#pragma unroll
      for (int i = 0; i < 4; i++)
#pragma unroll
        for (int j = 0; j < 2; j++) {
          acc[i][j] = __builtin_amdgcn_mfma_f32_16x16x32_bf16(ah[i], bh[j], acc[i][j], 0, 0, 0);
          acc[i][j] = __builtin_amdgcn_mfma_f32_16x16x32_bf16(ah[i], bl[j], acc[i][j], 0, 0, 0);
          acc[i][j] = __builtin_amdgcn_mfma_f32_16x16x32_bf16(al[i], bh[j], acc[i][j], 0, 0, 0);
        }
    } else {
#pragma unroll
      for (int i = 0; i < 4; i++)
#pragma unroll
        for (int j = 0; j < 2; j++)
          acc[i][j] = __builtin_amdgcn_mfma_f32_16x16x32_bf16(ah[i], bh[j], acc[i][j], 0, 0, 0);
    }
  }

  // epilogue: D layout col=lane&15, row=(lane>>4)*4+r
#pragma unroll
  for (int i = 0; i < 4; i++)
#pragma unroll
    for (int j = 0; j < 2; j++) {
      const int col = col0 + wc + j * 16 + lr;
      const float bval = bias[col];
#pragma unroll
      for (int r = 0; r < 4; r++) {
        const int row = row0 + wr + i * 16 + (lane >> 4) * 4 + r;
        const float v = acc[i][j][r] + bval;
        if constexpr (TOSPLIT) {
          const int b = row >> 11, l2 = row & (SEQ - 1);
          const int h = col >> 6, dk = col & 63;
          out[((size_t)(b * NH + h) * SEQ + l2) * DH + dk] = v;
        } else {
          out[(size_t)row * DM + col] = v;
        }
      }
    }
}

// ---------------------------------------------------------------------------
// M[b,h,q] = max_j(Q[bhq]·K[bh,idx[q,j]]) - sum_j(...)/SEQ.  One wave per row.
// ---------------------------------------------------------------------------
__global__ __launch_bounds__(256) void m_kernel(const float* __restrict__ Q,
                                                const float* __restrict__ K,
                                                const int* __restrict__ idxs,
                                                float* __restrict__ M) {
  const int lane = threadIdx.x & 63;
  const int r = blockIdx.x * 4 + (threadIdx.x >> 6);  // [0, BHROWS)
  const int q = r & (SEQ - 1);
  const int g = lane >> 3;        // sample group 0..7
  const int d8 = (lane & 7) * 8;  // dim slice start
  const float* Qr = Q + (size_t)r * DH + d8;
  const float4 q0 = *(const float4*)Qr;
  const float4 q1 = *(const float4*)(Qr + 4);
  const float* Kbh = K + (size_t)(r >> 11) * SEQ * DH;

  int ks[5];
#pragma unroll
  for (int p = 0; p < 5; p++) ks[p] = idxs[q * NS + g + 8 * p];
  float4 k0[5], k1[5];
#pragma unroll
  for (int p = 0; p < 5; p++) {
    const float* Kr = Kbh + (size_t)ks[p] * DH + d8;
    k0[p] = *(const float4*)Kr;
    k1[p] = *(const float4*)(Kr + 4);
  }
  float mx = -1e30f, sm = 0.f;
#pragma unroll
  for (int p = 0; p < 5; p++) {
    float acc = q0.x * k0[p].x + q0.y * k0[p].y + q0.z * k0[p].z + q0.w * k0[p].w +
                q1.x * k1[p].x + q1.y * k1[p].y + q1.z * k1[p].z + q1.w * k1[p].w;
    acc += __shfl_xor(acc, 1, 64);
    acc += __shfl_xor(acc, 2, 64);
    acc += __shfl_xor(acc, 4, 64);
    mx = fmaxf(mx, acc);
    sm += acc;
  }
#pragma unroll
  for (int o = 8; o <= 32; o <<= 1) {
    mx = fmaxf(mx, __shfl_xor(mx, o, 64));
    sm += __shfl_xor(sm, o, 64);
  }
  if (lane == 0) M[r] = mx - sm * (1.0f / (float)SEQ);
}

// ---------------------------------------------------------------------------
// Top-40 of M per (b,h). ONE WAVE per bh, all state in registers, no barriers.
// Lane owns stripe idx = j*64+lane (j=0..31, statically indexed -> VGPRs).
// Tie-break: lower index (matches jax top_k; butterfly all-reduce is exact).
// ---------------------------------------------------------------------------
__global__ __launch_bounds__(64) void topk_kernel(const float* __restrict__ M,
                                                  int* __restrict__ Mtop) {
  const int bh = blockIdx.x, lane = threadIdx.x;
  const float* Mb = M + (size_t)bh * SEQ;
  float v[32];
#pragma unroll
  for (int j = 0; j < 32; j++) v[j] = Mb[j * 64 + lane];

  // per-lane running max (lowest j wins ties -> lowest global idx per lane)
  float lmax = v[0];
  int lj = 0;
#pragma unroll
  for (int j = 1; j < 32; j++)
    if (v[j] > lmax) { lmax = v[j]; lj = j; }

  for (int it = 0; it < NT; it++) {
    float bm = lmax;
    int bidx = lj * 64 + lane;
#pragma unroll
    for (int o = 1; o <= 32; o <<= 1) {
      float ov = __shfl_xor(bm, o, 64);
      int oi = __shfl_xor(bidx, o, 64);
      if (ov > bm || (ov == bm && oi < bidx)) { bm = ov; bidx = oi; }
    }
    if (lane == 0) Mtop[bh * NT + it] = bidx;
    if ((bidx & 63) == lane) {   // winner lane: clear slot, rescan (static idx)
      const int rj = bidx >> 6;
#pragma unroll
      for (int j = 0; j < 32; j++)
        if (j == rj) v[j] = -1e30f;
      lmax = v[0];
      lj = 0;
#pragma unroll
      for (int j = 1; j < 32; j++)
        if (v[j] > lmax) { lmax = v[j]; lj = j; }
    }
  }
}

// ---------------------------------------------------------------------------
// V_sum stage 1: partial[bh][c][dk] = sum of 128 rows. Grid (32, 16).
// ---------------------------------------------------------------------------
__global__ __launch_bounds__(256) void vsum1_kernel(const float* __restrict__ V,
                                                    float* __restrict__ part) {
  __shared__ float sm[4][DH];
  const int bh = blockIdx.x, c = blockIdx.y, tid = threadIdx.x;
  const int dk = tid & 63, p = tid >> 6;
  const float* Vb = V + ((size_t)bh * SEQ + c * (SEQ / VCH)) * DH;
  float s = 0.f;
  for (int l = p; l < SEQ / VCH; l += 4) s += Vb[(size_t)l * DH + dk];
  sm[p][dk] = s;
  __syncthreads();
  if (p == 0)
    part[(size_t)(bh * VCH + c) * DH + dk] = sm[0][dk] + sm[1][dk] + sm[2][dk] + sm[3][dk];
}

__global__ __launch_bounds__(64) void vsum2_kernel(const float* __restrict__ part,
                                                   float* __restrict__ Vsum) {
  const int bh = blockIdx.x, dk = threadIdx.x;
  float s = 0.f;
#pragma unroll
  for (int c = 0; c < VCH; c++) s += part[(size_t)(bh * VCH + c) * DH + dk];
  Vsum[bh * DH + dk] = s;
}

// ---------------------------------------------------------------------------
// ctxT (B,L,D): V_sum broadcast (selected rows overwritten by reduce_scatter).
// ---------------------------------------------------------------------------
__global__ __launch_bounds__(256) void ctxinit_kernel(const float* __restrict__ Vsum,
                                                      float* __restrict__ ctxT) {
  const int idx = blockIdx.x * 256 + threadIdx.x;  // float4 index
  const int f = idx * 4;
  const int d = f & (DM - 1), b = f >> 20;
  float4 v = *(const float4*)&Vsum[b * DM + d];
  *(float4*)&ctxT[f] = v;
}

// ---------------------------------------------------------------------------
// scores[bh,u,s] = (Q[bh,Mtop[u]] · K[bh,s]) / 8.  Block: (bh, s-chunk of 256).
// ---------------------------------------------------------------------------
__global__ __launch_bounds__(256) void scores_kernel(const float* __restrict__ Q,
                                                     const float* __restrict__ K,
                                                     const int* __restrict__ Mtop,
                                                     float* __restrict__ scores) {
  __shared__ float Qs[NT * DH];
  const int bh = blockIdx.x, tid = threadIdx.x;
  for (int i = tid; i < NT * DH; i += 256) {
    int u = i >> 6, dk = i & 63;
    int row = Mtop[bh * NT + u];
    Qs[i] = Q[((size_t)bh * SEQ + row) * DH + dk];
  }
  __syncthreads();
  const int s = blockIdx.y * 256 + tid;
  const float* Krow = K + ((size_t)bh * SEQ + s) * DH;
  float4 kr[16];
#pragma unroll
  for (int g = 0; g < 16; g++) kr[g] = *(const float4*)&Krow[g * 4];
  for (int u = 0; u < NT; u++) {
    float acc = 0.f;
#pragma unroll
    for (int g = 0; g < 16; g++) {
      float4 qv = *(const float4*)&Qs[u * DH + g * 4];
      acc = fmaf(qv.x, kr[g].x, acc);
      acc = fmaf(qv.y, kr[g].y, acc);
      acc = fmaf(qv.z, kr[g].z, acc);
      acc = fmaf(qv.w, kr[g].w, acc);
    }
    scores[((size_t)bh * NT + u) * SEQ + s] = acc * 0.125f;
  }
}

// ---------------------------------------------------------------------------
// Row softmax over 2048, in place. One block per (bh,u) row.
// ---------------------------------------------------------------------------
__global__ __launch_bounds__(256) void softmax_kernel(float* __restrict__ scores) {
  __shared__ float red[256];
  const int row = blockIdx.x, tid = threadIdx.x;
  float* p = scores + (size_t)row * SEQ;
  float4 v0 = *(const float4*)&p[tid * 4];
  float4 v1 = *(const float4*)&p[1024 + tid * 4];
  float mx = fmaxf(fmaxf(fmaxf(v0.x, v0.y), fmaxf(v0.z, v0.w)),
                   fmaxf(fmaxf(v1.x, v1.y), fmaxf(v1.z, v1.w)));
  red[tid] = mx;
  __syncthreads();
  for (int s = 128; s; s >>= 1) {
    if (tid < s) red[tid] = fmaxf(red[tid], red[tid + s]);
    __syncthreads();
  }
  mx = red[0];
  __syncthreads();
  v0.x = __expf(v0.x - mx); v0.y = __expf(v0.y - mx);
  v0.z = __expf(v0.z - mx); v0.w = __expf(v0.w - mx);
  v1.x = __expf(v1.x - mx); v1.y = __expf(v1.y - mx);
  v1.z = __expf(v1.z - mx); v1.w = __expf(v1.w - mx);
  float sm = v0.x + v0.y + v0.z + v0.w + v1.x + v1.y + v1.z + v1.w;
  red[tid] = sm;
  __syncthreads();
  for (int s = 128; s; s >>= 1) {
    if (tid < s) red[tid] += red[tid + s];
    __syncthreads();
  }
  float inv = 1.0f / red[0];
  v0.x *= inv; v0.y *= inv; v0.z *= inv; v0.w *= inv;
  v1.x *= inv; v1.y *= inv; v1.z *= inv; v1.w *= inv;
  *(float4*)&p[tid * 4] = v0;
  *(float4*)&p[1024 + tid * 4] = v1;
}

// ---------------------------------------------------------------------------
// Partial upd = attn @ V over one 256-wide s-chunk. No atomics.
// ---------------------------------------------------------------------------
__global__ __launch_bounds__(256) void pv_partial_kernel(const float* __restrict__ attn,
                                                         const float* __restrict__ V,
                                                         float* __restrict__ updp) {
  __shared__ float Vl[64 * DH];
  __shared__ float Al2[NT * 64];
  const int bh = blockIdx.x, sc = blockIdx.y, tid = threadIdx.x;
  const int s0 = sc * 256;
  const int wid = tid >> 6, dk = tid & 63;
  float acc[10] = {};

  for (int st = 0; st < 4; st++) {
    const int sb = s0 + st * 64;
    __syncthreads();
#pragma unroll
    for (int i = 0; i < 16; i++) {
      int idx = tid + i * 256;
      int sj = idx >> 6, d2 = idx & 63;
      Vl[idx] = V[((size_t)bh * SEQ + sb + sj) * DH + d2];
    }
#pragma unroll
    for (int i = 0; i < 10; i++) {
      int idx = tid + i * 256;
      int u = idx >> 6, sj = idx & 63;
      Al2[idx] = attn[((size_t)bh * NT + u) * SEQ + sb + sj];
    }
    __syncthreads();
    for (int g = 0; g < 16; g++) {
      float a[10][4];
#pragma unroll
      for (int i = 0; i < 10; i++) {
        float4 t = *(const float4*)&Al2[(wid + 4 * i) * 64 + g * 4];
        a[i][0] = t.x; a[i][1] = t.y; a[i][2] = t.z; a[i][3] = t.w;
      }
#pragma unroll
      for (int t = 0; t < 4; t++) {
        float v = Vl[(g * 4 + t) * DH + dk];
#pragma unroll
        for (int i = 0; i < 10; i++) acc[i] = fmaf(a[i][t], v, acc[i]);
      }
    }
  }

#pragma unroll
  for (int i = 0; i < 10; i++) {
    int u = wid + 4 * i;
    updp[((size_t)(bh * NSC + sc) * NT + u) * DH + dk] = acc[i];
  }
}

// ---------------------------------------------------------------------------
// Sum the NSC partials in fixed order, overwrite selected ctxT rows.
// ---------------------------------------------------------------------------
__global__ __launch_bounds__(256) void reduce_scatter_kernel(const float* __restrict__ updp,
                                                             const int* __restrict__ Mtop,
                                                             float* __restrict__ ctxT) {
  const int bh = blockIdx.x;
  const int u = blockIdx.y * 4 + (threadIdx.x >> 6);
  const int dk = threadIdx.x & 63;
  float s = 0.f;
#pragma unroll
  for (int sc = 0; sc < NSC; sc++)
    s += updp[((size_t)(bh * NSC + sc) * NT + u) * DH + dk];
  const int row = Mtop[bh * NT + u];
  const int b = bh >> 3, h = bh & 7;
  ctxT[((size_t)b * SEQ + row) * DM + h * DH + dk] = s;
}

// ---------------------------------------------------------------------------
extern "C" void kernel_launch(void* const* d_in, const int* in_sizes, int n_in,
                              void* d_out, int out_size, void* d_ws, size_t ws_size,
                              hipStream_t stream) {
  (void)in_sizes; (void)n_in; (void)out_size; (void)ws_size;
  const float* queries = (const float*)d_in[0];
  const float* keys    = (const float*)d_in[1];
  const float* values  = (const float*)d_in[2];
  const int* index_sample = (const int*)d_in[4];
  const float* Wq = (const float*)d_in[5];
  const float* bq = (const float*)d_in[6];
  const float* Wk = (const float*)d_in[7];
  const float* bk = (const float*)d_in[8];
  const float* Wv = (const float*)d_in[9];
  const float* bv = (const float*)d_in[10];
  const float* Wo = (const float*)d_in[11];
  const float* bo = (const float*)d_in[12];
  float* out = (float*)d_out;

  // ws (floats): Q,Kp,Vp,ctxT 4x 4,194,304; scores 2,621,440; M 65,536;
  // Vsum 2,048; vpart 32,768; Mtop ints  => ~78 MB (same as round 5).
  float* ws = (float*)d_ws;
  float* Q    = ws;
  float* Kp   = Q + (size_t)ROWS * DM;
  float* Vp   = Kp + (size_t)ROWS * DM;
  float* ctxT = Vp + (size_t)ROWS * DM;
  float* scores = ctxT + (size_t)ROWS * DM;
  float* M    = scores + (size_t)NB * NH * NT * SEQ;
  float* Vsum = M + BHROWS;
  float* vpart = Vsum + NB * NH * DH;
  int* Mtop   = (int*)(vpart + NB * NH * VCH * DH);
  float* updp = Q;

  u16* XH = (u16*)ctxT;
  u16* XL = XH + (size_t)ROWS * DM;
  u16* WH = (u16*)scores;
  u16* WL = WH + (size_t)DM * DM;
  u16* CH  = (u16*)scores;
  u16* WoH = CH + (size_t)ROWS * DM;

  const int n4x = ROWS * DM / 4;          // 1,048,576 float4s
  const dim3 gG(ROWS / 128, DM / 64);     // (64, 8)
  const dim3 gW(8, 8);

  // Q projection (split-bf16 3-pass)
  cvt_split_kernel<<<n4x / 256, 256, 0, stream>>>(queries, XH, XL, 1);
  cvt_wt_kernel<<<gW, 256, 0, stream>>>(Wq, WH, WL, 1);
  gemm_mfma<true, true><<<gG, 256, 0, stream>>>(XH, XL, WH, WL, bq, Q);
  // K projection (split-bf16 3-pass)
  cvt_split_kernel<<<n4x / 256, 256, 0, stream>>>(keys, XH, XL, 1);
  cvt_wt_kernel<<<gW, 256, 0, stream>>>(Wk, WH, WL, 1);
  gemm_mfma<true, true><<<gG, 256, 0, stream>>>(XH, XL, WH, WL, bk, Kp);
  // V projection (single-pass bf16)
  cvt_split_kernel<<<n4x / 256, 256, 0, stream>>>(values, XH, XL, 0);
  cvt_wt_kernel<<<gW, 256, 0, stream>>>(Wv, WH, WL, 0);
  gemm_mfma<false, true><<<gG, 256, 0, stream>>>(XH, XH, WH, WH, bv, Vp);

  m_kernel<<<BHROWS / 4, 256, 0, stream>>>(Q, Kp, index_sample, M);
  topk_kernel<<<NB * NH, 64, 0, stream>>>(M, Mtop);
  vsum1_kernel<<<dim3(NB * NH, VCH), 256, 0, stream>>>(Vp, vpart);
  vsum2_kernel<<<NB * NH, 64, 0, stream>>>(vpart, Vsum);
  ctxinit_kernel<<<(ROWS * DM / 4) / 256, 256, 0, stream>>>(Vsum, ctxT);
  scores_kernel<<<dim3(NB * NH, SEQ / 256), 256, 0, stream>>>(Q, Kp, Mtop, scores);
  softmax_kernel<<<NB * NH * NT, 256, 0, stream>>>(scores);
  pv_partial_kernel<<<dim3(NB * NH, NSC), 256, 0, stream>>>(scores, Vp, updp);
  reduce_scatter_kernel<<<dim3(NB * NH, NT / 4), 256, 0, stream>>>(updp, Mtop, ctxT);

  // Output projection (single-pass bf16)
  cvt_split_kernel<<<n4x / 256, 256, 0, stream>>>(ctxT, CH, CH, 0);
  cvt_wt_kernel<<<gW, 256, 0, stream>>>(Wo, WoH, WoH, 0);
  gemm_mfma<false, false><<<gG, 256, 0, stream>>>(CH, CH, WoH, WoH, bo, out);
}

// Round 7
// 255.994 us; speedup vs baseline: 2.5360x; 1.0037x over previous
//
#include <hip/hip_runtime.h>

// ProbSparse attention (Informer) — B=4, L=2048, D=512, H=8, DK=64, SK=NTOP=40
// Round 7: top-k with 32 NAMED u64 key registers per lane (R6's float v[32]
// was scratch-demoted: VGPR_Count=24, time unchanged at 44.6us).
// Everything else unchanged from R6.

typedef unsigned short u16;
typedef unsigned long long u64;
typedef __attribute__((ext_vector_type(8))) short short8;
typedef __attribute__((ext_vector_type(4))) float f32x4;

constexpr int NB = 4;       // batch
constexpr int SEQ = 2048;   // L
constexpr int DM = 512;     // D
constexpr int NH = 8;
constexpr int DH = 64;      // DK
constexpr int NS = 40;      // SK (samples)
constexpr int NT = 40;      // NTOP
constexpr int ROWS = NB * SEQ;          // 8192
constexpr int BHROWS = NB * NH * SEQ;   // 65536
constexpr int NSC = 8;      // s-chunks in pv (SEQ/256)
constexpr int VCH = 16;     // vsum l-chunks per (b,h)

#define R32(X) X(0) X(1) X(2) X(3) X(4) X(5) X(6) X(7) \
               X(8) X(9) X(10) X(11) X(12) X(13) X(14) X(15) \
               X(16) X(17) X(18) X(19) X(20) X(21) X(22) X(23) \
               X(24) X(25) X(26) X(27) X(28) X(29) X(30) X(31)

// ---------------------------------------------------------------------------
// bf16 helpers (round-to-nearest-even)
// ---------------------------------------------------------------------------
__device__ __forceinline__ u16 f2bf(float x) {
  union { float f; unsigned u; } v; v.f = x;
  unsigned r = v.u + 0x7FFFu + ((v.u >> 16) & 1u);
  return (u16)(r >> 16);
}
__device__ __forceinline__ float bf2f(u16 b) {
  union { unsigned u; float f; } v; v.u = ((unsigned)b) << 16;
  return v.f;
}

__device__ __forceinline__ void gload16(void* lds, const void* g) {
  __builtin_amdgcn_global_load_lds(
      (const __attribute__((address_space(1))) unsigned int*)g,
      (__attribute__((address_space(3))) unsigned int*)lds, 16, 0, 0);
}

// ---------------------------------------------------------------------------
// X (R x 512 fp32, row-major) -> H (+L) bf16, same layout. One float4/thread.
// ---------------------------------------------------------------------------
__global__ __launch_bounds__(256) void cvt_split_kernel(const float* __restrict__ X,
                                                        u16* __restrict__ H,
                                                        u16* __restrict__ L,
                                                        int doLo) {
  const int i = blockIdx.x * 256 + threadIdx.x;
  float4 v = ((const float4*)X)[i];
  ushort4 h;
  h.x = f2bf(v.x); h.y = f2bf(v.y); h.z = f2bf(v.z); h.w = f2bf(v.w);
  ((ushort4*)H)[i] = h;
  if (doLo) {
    ushort4 l;
    l.x = f2bf(v.x - bf2f(h.x)); l.y = f2bf(v.y - bf2f(h.y));
    l.z = f2bf(v.z - bf2f(h.z)); l.w = f2bf(v.w - bf2f(h.w));
    ((ushort4*)L)[i] = l;
  }
}

// ---------------------------------------------------------------------------
// W (512x512 fp32, [k][n]) -> Wt bf16 [n][k] hi (+lo). 64x64 tiles, grid (8,8).
// ---------------------------------------------------------------------------
__global__ __launch_bounds__(256) void cvt_wt_kernel(const float* __restrict__ W,
                                                     u16* __restrict__ H,
                                                     u16* __restrict__ L,
                                                     int doLo) {
  __shared__ float T[64][65];
  const int c0 = blockIdx.x * 64;  // n
  const int r0 = blockIdx.y * 64;  // k
  const int t = threadIdx.x;
  const int lr = t >> 4, lc4 = (t & 15) * 4;
#pragma unroll
  for (int i = 0; i < 4; i++) {
    float4 v = *(const float4*)&W[(size_t)(r0 + lr + i * 16) * DM + c0 + lc4];
    T[lr + i * 16][lc4 + 0] = v.x;
    T[lr + i * 16][lc4 + 1] = v.y;
    T[lr + i * 16][lc4 + 2] = v.z;
    T[lr + i * 16][lc4 + 3] = v.w;
  }
  __syncthreads();
#pragma unroll
  for (int i = 0; i < 4; i++) {
    const int n = lr + i * 16;
    float x0 = T[lc4 + 0][n], x1 = T[lc4 + 1][n], x2 = T[lc4 + 2][n], x3 = T[lc4 + 3][n];
    ushort4 h;
    h.x = f2bf(x0); h.y = f2bf(x1); h.z = f2bf(x2); h.w = f2bf(x3);
    *(ushort4*)&H[(size_t)(c0 + n) * DM + r0 + lc4] = h;
    if (doLo) {
      ushort4 l;
      l.x = f2bf(x0 - bf2f(h.x)); l.y = f2bf(x1 - bf2f(h.y));
      l.z = f2bf(x2 - bf2f(h.z)); l.w = f2bf(x3 - bf2f(h.w));
      *(ushort4*)&L[(size_t)(c0 + n) * DM + r0 + lc4] = l;
    }
  }
}

// ---------------------------------------------------------------------------
// MFMA GEMM: C(8192x512) = X(8192x512) @ W(512x512) + bias, bf16 inputs.
// 128(M) x 64(N) tile, BK=32, 256 thr, 4 waves (2x2), wave tile 64x32.
// SPLIT3: 3-pass split-bf16 (Ah*Bh + Ah*Bl + Al*Bh). TOSPLIT: (B,H,L,DH) out.
// ---------------------------------------------------------------------------
template <bool SPLIT3, bool TOSPLIT>
__global__ __launch_bounds__(256) void gemm_mfma(const u16* __restrict__ XH,
                                                 const u16* __restrict__ XL,
                                                 const u16* __restrict__ WTH,
                                                 const u16* __restrict__ WTL,
                                                 const float* __restrict__ bias,
                                                 float* __restrict__ out) {
  __shared__ __align__(16) u16 Ah[128 * 32];
  __shared__ __align__(16) u16 Al[128 * 32];
  __shared__ __align__(16) u16 Bh[64 * 32];
  __shared__ __align__(16) u16 Bl[64 * 32];
  const int tid = threadIdx.x, lane = tid & 63, w = tid >> 6;
  const int row0 = blockIdx.x * 128, col0 = blockIdx.y * 64;
  const int wr = (w >> 1) * 64, wc = (w & 1) * 32;
  const int lr = lane & 15, kb8 = (lane >> 4) * 8;
  const int mrow = lane >> 2;          // row within 16-row chunk
  const int kcol = (lane & 3) * 8;     // bf16 elements into the 32-wide k slab

  f32x4 acc[4][2];
#pragma unroll
  for (int i = 0; i < 4; i++)
#pragma unroll
    for (int j = 0; j < 2; j++) acc[i][j] = (f32x4){0.f, 0.f, 0.f, 0.f};

  constexpr int PER = SPLIT3 ? 6 : 3;  // staging chunks per wave

  for (int k0 = 0; k0 < DM; k0 += 32) {
    __syncthreads();
#pragma unroll
    for (int i = 0; i < PER; i++) {
      const int c = w * PER + i;
      const u16* g;
      u16* l;
      if (SPLIT3) {
        if (c < 8)       { g = XH  + (size_t)(row0 + c * 16 + mrow) * DM + k0 + kcol;        l = Ah + c * 512; }
        else if (c < 16) { g = XL  + (size_t)(row0 + (c - 8) * 16 + mrow) * DM + k0 + kcol;  l = Al + (c - 8) * 512; }
        else if (c < 20) { g = WTH + (size_t)(col0 + (c - 16) * 16 + mrow) * DM + k0 + kcol; l = Bh + (c - 16) * 512; }
        else             { g = WTL + (size_t)(col0 + (c - 20) * 16 + mrow) * DM + k0 + kcol; l = Bl + (c - 20) * 512; }
      } else {
        if (c < 8)       { g = XH  + (size_t)(row0 + c * 16 + mrow) * DM + k0 + kcol;        l = Ah + c * 512; }
        else             { g = WTH + (size_t)(col0 + (c - 8) * 16 + mrow) * DM + k0 + kcol;  l = Bh + (c - 8) * 512; }
      }
      gload16(l, g);
    }
    __syncthreads();

    short8 ah[4], bh[2];
#pragma unroll
    for (int i = 0; i < 4; i++) ah[i] = *(const short8*)&Ah[(wr + i * 16 + lr) * 32 + kb8];
#pragma unroll
    for (int j = 0; j < 2; j++) bh[j] = *(const short8*)&Bh[(wc + j * 16 + lr) * 32 + kb8];
    if constexpr (SPLIT3) {
      short8 al[4], bl[2];
#pragma unroll
      for (int i = 0; i < 4; i++) al[i] = *(const short8*)&Al[(wr + i * 16 + lr) * 32 + kb8];
#pragma unroll
      for (int j = 0; j < 2; j++) bl[j] = *(const short8*)&Bl[(wc + j * 16 + lr) * 32 + kb8];
#pragma unroll
      for (int i = 0; i < 4; i++)
#pragma unroll
        for (int j = 0; j < 2; j++) {
          acc[i][j] = __builtin_amdgcn_mfma_f32_16x16x32_bf16(ah[i], bh[j], acc[i][j], 0, 0, 0);
          acc[i][j] = __builtin_amdgcn_mfma_f32_16x16x32_bf16(ah[i], bl[j], acc[i][j], 0, 0, 0);
          acc[i][j] = __builtin_amdgcn_mfma_f32_16x16x32_bf16(al[i], bh[j], acc[i][j], 0, 0, 0);
        }
    } else {
#pragma unroll
      for (int i = 0; i < 4; i++)
#pragma unroll
        for (int j = 0; j < 2; j++)
          acc[i][j] = __builtin_amdgcn_mfma_f32_16x16x32_bf16(ah[i], bh[j], acc[i][j], 0, 0, 0);
    }
  }

  // epilogue: D layout col=lane&15, row=(lane>>4)*4+r
#pragma unroll
  for (int i = 0; i < 4; i++)
#pragma unroll
    for (int j = 0; j < 2; j++) {
      const int col = col0 + wc + j * 16 + lr;
      const float bval = bias[col];
#pragma unroll
      for (int r = 0; r < 4; r++) {
        const int row = row0 + wr + i * 16 + (lane >> 4) * 4 + r;
        const float v = acc[i][j][r] + bval;
        if constexpr (TOSPLIT) {
          const int b = row >> 11, l2 = row & (SEQ - 1);
          const int h = col >> 6, dk = col & 63;
          out[((size_t)(b * NH + h) * SEQ + l2) * DH + dk] = v;
        } else {
          out[(size_t)row * DM + col] = v;
        }
      }
    }
}

// ---------------------------------------------------------------------------
// M[b,h,q] = max_j(Q[bhq]·K[bh,idx[q,j]]) - sum_j(...)/SEQ.  One wave per row.
// ---------------------------------------------------------------------------
__global__ __launch_bounds__(256) void m_kernel(const float* __restrict__ Q,
                                                const float* __restrict__ K,
                                                const int* __restrict__ idxs,
                                                float* __restrict__ M) {
  const int lane = threadIdx.x & 63;
  const int r = blockIdx.x * 4 + (threadIdx.x >> 6);  // [0, BHROWS)
  const int q = r & (SEQ - 1);
  const int g = lane >> 3;        // sample group 0..7
  const int d8 = (lane & 7) * 8;  // dim slice start
  const float* Qr = Q + (size_t)r * DH + d8;
  const float4 q0 = *(const float4*)Qr;
  const float4 q1 = *(const float4*)(Qr + 4);
  const float* Kbh = K + (size_t)(r >> 11) * SEQ * DH;

  int ks[5];
#pragma unroll
  for (int p = 0; p < 5; p++) ks[p] = idxs[q * NS + g + 8 * p];
  float4 k0[5], k1[5];
#pragma unroll
  for (int p = 0; p < 5; p++) {
    const float* Kr = Kbh + (size_t)ks[p] * DH + d8;
    k0[p] = *(const float4*)Kr;
    k1[p] = *(const float4*)(Kr + 4);
  }
  float mx = -1e30f, sm = 0.f;
#pragma unroll
  for (int p = 0; p < 5; p++) {
    float acc = q0.x * k0[p].x + q0.y * k0[p].y + q0.z * k0[p].z + q0.w * k0[p].w +
                q1.x * k1[p].x + q1.y * k1[p].y + q1.z * k1[p].z + q1.w * k1[p].w;
    acc += __shfl_xor(acc, 1, 64);
    acc += __shfl_xor(acc, 2, 64);
    acc += __shfl_xor(acc, 4, 64);
    mx = fmaxf(mx, acc);
    sm += acc;
  }
#pragma unroll
  for (int o = 8; o <= 32; o <<= 1) {
    mx = fmaxf(mx, __shfl_xor(mx, o, 64));
    sm += __shfl_xor(sm, o, 64);
  }
  if (lane == 0) M[r] = mx - sm * (1.0f / (float)SEQ);
}

// ---------------------------------------------------------------------------
// Top-40 of M per (b,h). ONE WAVE per bh; 32 NAMED u64 keys per lane (no
// array -> no scratch demotion). key = ordered(float)<<32 | ~idx: max(key)
// gives argmax with lower-index tie-break (= jax top_k). Cleared slot = 0
// (< any real key: lo 32 bits of real keys are ~idx >= 0xFFFFF800).
// ---------------------------------------------------------------------------
__global__ __launch_bounds__(64) void topk_kernel(const float* __restrict__ M,
                                                  int* __restrict__ Mtop) {
  const int bh = blockIdx.x, lane = threadIdx.x;
  const float* Mb = M + (size_t)bh * SEQ;

#define DECLK(J) u64 k##J;
  R32(DECLK)
#undef DECLK
#define LOADK(J) { \
    unsigned ub = __float_as_uint(Mb[J * 64 + lane]); \
    ub ^= (ub >> 31) ? 0xFFFFFFFFu : 0x80000000u; \
    k##J = ((u64)ub << 32) | (u64)(unsigned)~(unsigned)(J * 64 + lane); }
  R32(LOADK)
#undef LOADK

  u64 lmax = 0;
#define MAXK(J) if (k##J > lmax) lmax = k##J;
  R32(MAXK)

  for (int it = 0; it < NT; it++) {
    u64 b = lmax;
#pragma unroll
    for (int o = 1; o <= 32; o <<= 1) {
      u64 ov = __shfl_xor(b, o, 64);
      if (ov > b) b = ov;
    }
    if (lane == 0) Mtop[bh * NT + it] = (int)(unsigned)~(unsigned)b;
    if (lmax == b) {  // unique winner lane (keys are unique)
#define CLRK(J) if (k##J == b) k##J = 0;
      R32(CLRK)
#undef CLRK
      lmax = 0;
      R32(MAXK)
    }
  }
#undef MAXK
}

// ---------------------------------------------------------------------------
// V_sum stage 1: partial[bh][c][dk] = sum of 128 rows. Grid (32, 16).
// ---------------------------------------------------------------------------
__global__ __launch_bounds__(256) void vsum1_kernel(const float* __restrict__ V,
                                                    float* __restrict__ part) {
  __shared__ float sm[4][DH];
  const int bh = blockIdx.x, c = blockIdx.y, tid = threadIdx.x;
  const int dk = tid & 63, p = tid >> 6;
  const float* Vb = V + ((size_t)bh * SEQ + c * (SEQ / VCH)) * DH;
  float s = 0.f;
  for (int l = p; l < SEQ / VCH; l += 4) s += Vb[(size_t)l * DH + dk];
  sm[p][dk] = s;
  __syncthreads();
  if (p == 0)
    part[(size_t)(bh * VCH + c) * DH + dk] = sm[0][dk] + sm[1][dk] + sm[2][dk] + sm[3][dk];
}

__global__ __launch_bounds__(64) void vsum2_kernel(const float* __restrict__ part,
                                                   float* __restrict__ Vsum) {
  const int bh = blockIdx.x, dk = threadIdx.x;
  float s = 0.f;
#pragma unroll
  for (int c = 0; c < VCH; c++) s += part[(size_t)(bh * VCH + c) * DH + dk];
  Vsum[bh * DH + dk] = s;
}

// ---------------------------------------------------------------------------
// ctxT (B,L,D): V_sum broadcast (selected rows overwritten by reduce_scatter).
// ---------------------------------------------------------------------------
__global__ __launch_bounds__(256) void ctxinit_kernel(const float* __restrict__ Vsum,
                                                      float* __restrict__ ctxT) {
  const int idx = blockIdx.x * 256 + threadIdx.x;  // float4 index
  const int f = idx * 4;
  const int d = f & (DM - 1), b = f >> 20;
  float4 v = *(const float4*)&Vsum[b * DM + d];
  *(float4*)&ctxT[f] = v;
}

// ---------------------------------------------------------------------------
// scores[bh,u,s] = (Q[bh,Mtop[u]] · K[bh,s]) / 8.  Block: (bh, s-chunk of 256).
// ---------------------------------------------------------------------------
__global__ __launch_bounds__(256) void scores_kernel(const float* __restrict__ Q,
                                                     const float* __restrict__ K,
                                                     const int* __restrict__ Mtop,
                                                     float* __restrict__ scores) {
  __shared__ float Qs[NT * DH];
  const int bh = blockIdx.x, tid = threadIdx.x;
  for (int i = tid; i < NT * DH; i += 256) {
    int u = i >> 6, dk = i & 63;
    int row = Mtop[bh * NT + u];
    Qs[i] = Q[((size_t)bh * SEQ + row) * DH + dk];
  }
  __syncthreads();
  const int s = blockIdx.y * 256 + tid;
  const float* Krow = K + ((size_t)bh * SEQ + s) * DH;
  float4 kr[16];
#pragma unroll
  for (int g = 0; g < 16; g++) kr[g] = *(const float4*)&Krow[g * 4];
  for (int u = 0; u < NT; u++) {
    float acc = 0.f;
#pragma unroll
    for (int g = 0; g < 16; g++) {
      float4 qv = *(const float4*)&Qs[u * DH + g * 4];
      acc = fmaf(qv.x, kr[g].x, acc);
      acc = fmaf(qv.y, kr[g].y, acc);
      acc = fmaf(qv.z, kr[g].z, acc);
      acc = fmaf(qv.w, kr[g].w, acc);
    }
    scores[((size_t)bh * NT + u) * SEQ + s] = acc * 0.125f;
  }
}

// ---------------------------------------------------------------------------
// Row softmax over 2048, in place. One block per (bh,u) row.
// ---------------------------------------------------------------------------
__global__ __launch_bounds__(256) void softmax_kernel(float* __restrict__ scores) {
  __shared__ float red[256];
  const int row = blockIdx.x, tid = threadIdx.x;
  float* p = scores + (size_t)row * SEQ;
  float4 v0 = *(const float4*)&p[tid * 4];
  float4 v1 = *(const float4*)&p[1024 + tid * 4];
  float mx = fmaxf(fmaxf(fmaxf(v0.x, v0.y), fmaxf(v0.z, v0.w)),
                   fmaxf(fmaxf(v1.x, v1.y), fmaxf(v1.z, v1.w)));
  red[tid] = mx;
  __syncthreads();
  for (int s = 128; s; s >>= 1) {
    if (tid < s) red[tid] = fmaxf(red[tid], red[tid + s]);
    __syncthreads();
  }
  mx = red[0];
  __syncthreads();
  v0.x = __expf(v0.x - mx); v0.y = __expf(v0.y - mx);
  v0.z = __expf(v0.z - mx); v0.w = __expf(v0.w - mx);
  v1.x = __expf(v1.x - mx); v1.y = __expf(v1.y - mx);
  v1.z = __expf(v1.z - mx); v1.w = __expf(v1.w - mx);
  float sm = v0.x + v0.y + v0.z + v0.w + v1.x + v1.y + v1.z + v1.w;
  red[tid] = sm;
  __syncthreads();
  for (int s = 128; s; s >>= 1) {
    if (tid < s) red[tid] += red[tid + s];
    __syncthreads();
  }
  float inv = 1.0f / red[0];
  v0.x *= inv; v0.y *= inv; v0.z *= inv; v0.w *= inv;
  v1.x *= inv; v1.y *= inv; v1.z *= inv; v1.w *= inv;
  *(float4*)&p[tid * 4] = v0;
  *(float4*)&p[1024 + tid * 4] = v1;
}

// ---------------------------------------------------------------------------
// Partial upd = attn @ V over one 256-wide s-chunk. No atomics.
// ---------------------------------------------------------------------------
__global__ __launch_bounds__(256) void pv_partial_kernel(const float* __restrict__ attn,
                                                         const float* __restrict__ V,
                                                         float* __restrict__ updp) {
  __shared__ float Vl[64 * DH];
  __shared__ float Al2[NT * 64];
  const int bh = blockIdx.x, sc = blockIdx.y, tid = threadIdx.x;
  const int s0 = sc * 256;
  const int wid = tid >> 6, dk = tid & 63;
  float acc[10] = {};

  for (int st = 0; st < 4; st++) {
    const int sb = s0 + st * 64;
    __syncthreads();
#pragma unroll
    for (int i = 0; i < 16; i++) {
      int idx = tid + i * 256;
      int sj = idx >> 6, d2 = idx & 63;
      Vl[idx] = V[((size_t)bh * SEQ + sb + sj) * DH + d2];
    }
#pragma unroll
    for (int i = 0; i < 10; i++) {
      int idx = tid + i * 256;
      int u = idx >> 6, sj = idx & 63;
      Al2[idx] = attn[((size_t)bh * NT + u) * SEQ + sb + sj];
    }
    __syncthreads();
    for (int g = 0; g < 16; g++) {
      float a[10][4];
#pragma unroll
      for (int i = 0; i < 10; i++) {
        float4 t = *(const float4*)&Al2[(wid + 4 * i) * 64 + g * 4];
        a[i][0] = t.x; a[i][1] = t.y; a[i][2] = t.z; a[i][3] = t.w;
      }
#pragma unroll
      for (int t = 0; t < 4; t++) {
        float v = Vl[(g * 4 + t) * DH + dk];
#pragma unroll
        for (int i = 0; i < 10; i++) acc[i] = fmaf(a[i][t], v, acc[i]);
      }
    }
  }

#pragma unroll
  for (int i = 0; i < 10; i++) {
    int u = wid + 4 * i;
    updp[((size_t)(bh * NSC + sc) * NT + u) * DH + dk] = acc[i];
  }
}

// ---------------------------------------------------------------------------
// Sum the NSC partials in fixed order, overwrite selected ctxT rows.
// ---------------------------------------------------------------------------
__global__ __launch_bounds__(256) void reduce_scatter_kernel(const float* __restrict__ updp,
                                                             const int* __restrict__ Mtop,
                                                             float* __restrict__ ctxT) {
  const int bh = blockIdx.x;
  const int u = blockIdx.y * 4 + (threadIdx.x >> 6);
  const int dk = threadIdx.x & 63;
  float s = 0.f;
#pragma unroll
  for (int sc = 0; sc < NSC; sc++)
    s += updp[((size_t)(bh * NSC + sc) * NT + u) * DH + dk];
  const int row = Mtop[bh * NT + u];
  const int b = bh >> 3, h = bh & 7;
  ctxT[((size_t)b * SEQ + row) * DM + h * DH + dk] = s;
}

// ---------------------------------------------------------------------------
extern "C" void kernel_launch(void* const* d_in, const int* in_sizes, int n_in,
                              void* d_out, int out_size, void* d_ws, size_t ws_size,
                              hipStream_t stream) {
  (void)in_sizes; (void)n_in; (void)out_size; (void)ws_size;
  const float* queries = (const float*)d_in[0];
  const float* keys    = (const float*)d_in[1];
  const float* values  = (const float*)d_in[2];
  const int* index_sample = (const int*)d_in[4];
  const float* Wq = (const float*)d_in[5];
  const float* bq = (const float*)d_in[6];
  const float* Wk = (const float*)d_in[7];
  const float* bk = (const float*)d_in[8];
  const float* Wv = (const float*)d_in[9];
  const float* bv = (const float*)d_in[10];
  const float* Wo = (const float*)d_in[11];
  const float* bo = (const float*)d_in[12];
  float* out = (float*)d_out;

  // ws (floats): Q,Kp,Vp,ctxT 4x 4,194,304; scores 2,621,440; M 65,536;
  // Vsum 2,048; vpart 32,768; Mtop ints  => ~78 MB (same as round 6).
  float* ws = (float*)d_ws;
  float* Q    = ws;
  float* Kp   = Q + (size_t)ROWS * DM;
  float* Vp   = Kp + (size_t)ROWS * DM;
  float* ctxT = Vp + (size_t)ROWS * DM;
  float* scores = ctxT + (size_t)ROWS * DM;
  float* M    = scores + (size_t)NB * NH * NT * SEQ;
  float* Vsum = M + BHROWS;
  float* vpart = Vsum + NB * NH * DH;
  int* Mtop   = (int*)(vpart + NB * NH * VCH * DH);
  float* updp = Q;

  u16* XH = (u16*)ctxT;
  u16* XL = XH + (size_t)ROWS * DM;
  u16* WH = (u16*)scores;
  u16* WL = WH + (size_t)DM * DM;
  u16* CH  = (u16*)scores;
  u16* WoH = CH + (size_t)ROWS * DM;

  const int n4x = ROWS * DM / 4;          // 1,048,576 float4s
  const dim3 gG(ROWS / 128, DM / 64);     // (64, 8)
  const dim3 gW(8, 8);

  // Q projection (split-bf16 3-pass)
  cvt_split_kernel<<<n4x / 256, 256, 0, stream>>>(queries, XH, XL, 1);
  cvt_wt_kernel<<<gW, 256, 0, stream>>>(Wq, WH, WL, 1);
  gemm_mfma<true, true><<<gG, 256, 0, stream>>>(XH, XL, WH, WL, bq, Q);
  // K projection (split-bf16 3-pass)
  cvt_split_kernel<<<n4x / 256, 256, 0, stream>>>(keys, XH, XL, 1);
  cvt_wt_kernel<<<gW, 256, 0, stream>>>(Wk, WH, WL, 1);
  gemm_mfma<true, true><<<gG, 256, 0, stream>>>(XH, XL, WH, WL, bk, Kp);
  // V projection (single-pass bf16)
  cvt_split_kernel<<<n4x / 256, 256, 0, stream>>>(values, XH, XL, 0);
  cvt_wt_kernel<<<gW, 256, 0, stream>>>(Wv, WH, WL, 0);
  gemm_mfma<false, true><<<gG, 256, 0, stream>>>(XH, XH, WH, WH, bv, Vp);

  m_kernel<<<BHROWS / 4, 256, 0, stream>>>(Q, Kp, index_sample, M);
  topk_kernel<<<NB * NH, 64, 0, stream>>>(M, Mtop);
  vsum1_kernel<<<dim3(NB * NH, VCH), 256, 0, stream>>>(Vp, vpart);
  vsum2_kernel<<<NB * NH, 64, 0, stream>>>(vpart, Vsum);
  ctxinit_kernel<<<(ROWS * DM / 4) / 256, 256, 0, stream>>>(Vsum, ctxT);
  scores_kernel<<<dim3(NB * NH, SEQ / 256), 256, 0, stream>>>(Q, Kp, Mtop, scores);
  softmax_kernel<<<NB * NH * NT, 256, 0, stream>>>(scores);
  pv_partial_kernel<<<dim3(NB * NH, NSC), 256, 0, stream>>>(scores, Vp, updp);
  reduce_scatter_kernel<<<dim3(NB * NH, NT / 4), 256, 0, stream>>>(updp, Mtop, ctxT);

  // Output projection (single-pass bf16)
  cvt_split_kernel<<<n4x / 256, 256, 0, stream>>>(ctxT, CH, CH, 0);
  cvt_wt_kernel<<<gW, 256, 0, stream>>>(Wo, WoH, WoH, 0);
  gemm_mfma<false, false><<<gG, 256, 0, stream>>>(CH, CH, WoH, WoH, bo, out);
}

// Round 8
// 240.471 us; speedup vs baseline: 2.6997x; 1.0646x over previous
//
#include <hip/hip_runtime.h>

// ProbSparse attention (Informer) — B=4, L=2048, D=512, H=8, DK=64, SK=NTOP=40
// Round 8: bitonic-sort top-k (R5/R6/R7 all ~43us: 40 serial iterations of a
// dependent DS chain at 1 wave/CU is latency-bound regardless of storage).
// Full 2048-key bitonic sort, 1024 threads (16 waves) per (b,h), take first 40.
// Everything else unchanged from R7.

typedef unsigned short u16;
typedef unsigned long long u64;
typedef __attribute__((ext_vector_type(8))) short short8;
typedef __attribute__((ext_vector_type(4))) float f32x4;

constexpr int NB = 4;       // batch
constexpr int SEQ = 2048;   // L
constexpr int DM = 512;     // D
constexpr int NH = 8;
constexpr int DH = 64;      // DK
constexpr int NS = 40;      // SK (samples)
constexpr int NT = 40;      // NTOP
constexpr int ROWS = NB * SEQ;          // 8192
constexpr int BHROWS = NB * NH * SEQ;   // 65536
constexpr int NSC = 8;      // s-chunks in pv (SEQ/256)
constexpr int VCH = 16;     // vsum l-chunks per (b,h)

// ---------------------------------------------------------------------------
// bf16 helpers (round-to-nearest-even)
// ---------------------------------------------------------------------------
__device__ __forceinline__ u16 f2bf(float x) {
  union { float f; unsigned u; } v; v.f = x;
  unsigned r = v.u + 0x7FFFu + ((v.u >> 16) & 1u);
  return (u16)(r >> 16);
}
__device__ __forceinline__ float bf2f(u16 b) {
  union { unsigned u; float f; } v; v.u = ((unsigned)b) << 16;
  return v.f;
}

__device__ __forceinline__ void gload16(void* lds, const void* g) {
  __builtin_amdgcn_global_load_lds(
      (const __attribute__((address_space(1))) unsigned int*)g,
      (__attribute__((address_space(3))) unsigned int*)lds, 16, 0, 0);
}

// ---------------------------------------------------------------------------
// X (R x 512 fp32, row-major) -> H (+L) bf16, same layout. One float4/thread.
// ---------------------------------------------------------------------------
__global__ __launch_bounds__(256) void cvt_split_kernel(const float* __restrict__ X,
                                                        u16* __restrict__ H,
                                                        u16* __restrict__ L,
                                                        int doLo) {
  const int i = blockIdx.x * 256 + threadIdx.x;
  float4 v = ((const float4*)X)[i];
  ushort4 h;
  h.x = f2bf(v.x); h.y = f2bf(v.y); h.z = f2bf(v.z); h.w = f2bf(v.w);
  ((ushort4*)H)[i] = h;
  if (doLo) {
    ushort4 l;
    l.x = f2bf(v.x - bf2f(h.x)); l.y = f2bf(v.y - bf2f(h.y));
    l.z = f2bf(v.z - bf2f(h.z)); l.w = f2bf(v.w - bf2f(h.w));
    ((ushort4*)L)[i] = l;
  }
}

// ---------------------------------------------------------------------------
// W (512x512 fp32, [k][n]) -> Wt bf16 [n][k] hi (+lo). 64x64 tiles, grid (8,8).
// ---------------------------------------------------------------------------
__global__ __launch_bounds__(256) void cvt_wt_kernel(const float* __restrict__ W,
                                                     u16* __restrict__ H,
                                                     u16* __restrict__ L,
                                                     int doLo) {
  __shared__ float T[64][65];
  const int c0 = blockIdx.x * 64;  // n
  const int r0 = blockIdx.y * 64;  // k
  const int t = threadIdx.x;
  const int lr = t >> 4, lc4 = (t & 15) * 4;
#pragma unroll
  for (int i = 0; i < 4; i++) {
    float4 v = *(const float4*)&W[(size_t)(r0 + lr + i * 16) * DM + c0 + lc4];
    T[lr + i * 16][lc4 + 0] = v.x;
    T[lr + i * 16][lc4 + 1] = v.y;
    T[lr + i * 16][lc4 + 2] = v.z;
    T[lr + i * 16][lc4 + 3] = v.w;
  }
  __syncthreads();
#pragma unroll
  for (int i = 0; i < 4; i++) {
    const int n = lr + i * 16;
    float x0 = T[lc4 + 0][n], x1 = T[lc4 + 1][n], x2 = T[lc4 + 2][n], x3 = T[lc4 + 3][n];
    ushort4 h;
    h.x = f2bf(x0); h.y = f2bf(x1); h.z = f2bf(x2); h.w = f2bf(x3);
    *(ushort4*)&H[(size_t)(c0 + n) * DM + r0 + lc4] = h;
    if (doLo) {
      ushort4 l;
      l.x = f2bf(x0 - bf2f(h.x)); l.y = f2bf(x1 - bf2f(h.y));
      l.z = f2bf(x2 - bf2f(h.z)); l.w = f2bf(x3 - bf2f(h.w));
      *(ushort4*)&L[(size_t)(c0 + n) * DM + r0 + lc4] = l;
    }
  }
}

// ---------------------------------------------------------------------------
// MFMA GEMM: C(8192x512) = X(8192x512) @ W(512x512) + bias, bf16 inputs.
// 128(M) x 64(N) tile, BK=32, 256 thr, 4 waves (2x2), wave tile 64x32.
// SPLIT3: 3-pass split-bf16 (Ah*Bh + Ah*Bl + Al*Bh). TOSPLIT: (B,H,L,DH) out.
// ---------------------------------------------------------------------------
template <bool SPLIT3, bool TOSPLIT>
__global__ __launch_bounds__(256) void gemm_mfma(const u16* __restrict__ XH,
                                                 const u16* __restrict__ XL,
                                                 const u16* __restrict__ WTH,
                                                 const u16* __restrict__ WTL,
                                                 const float* __restrict__ bias,
                                                 float* __restrict__ out) {
  __shared__ __align__(16) u16 Ah[128 * 32];
  __shared__ __align__(16) u16 Al[128 * 32];
  __shared__ __align__(16) u16 Bh[64 * 32];
  __shared__ __align__(16) u16 Bl[64 * 32];
  const int tid = threadIdx.x, lane = tid & 63, w = tid >> 6;
  const int row0 = blockIdx.x * 128, col0 = blockIdx.y * 64;
  const int wr = (w >> 1) * 64, wc = (w & 1) * 32;
  const int lr = lane & 15, kb8 = (lane >> 4) * 8;
  const int mrow = lane >> 2;          // row within 16-row chunk
  const int kcol = (lane & 3) * 8;     // bf16 elements into the 32-wide k slab

  f32x4 acc[4][2];
#pragma unroll
  for (int i = 0; i < 4; i++)
#pragma unroll
    for (int j = 0; j < 2; j++) acc[i][j] = (f32x4){0.f, 0.f, 0.f, 0.f};

  constexpr int PER = SPLIT3 ? 6 : 3;  // staging chunks per wave

  for (int k0 = 0; k0 < DM; k0 += 32) {
    __syncthreads();
#pragma unroll
    for (int i = 0; i < PER; i++) {
      const int c = w * PER + i;
      const u16* g;
      u16* l;
      if (SPLIT3) {
        if (c < 8)       { g = XH  + (size_t)(row0 + c * 16 + mrow) * DM + k0 + kcol;        l = Ah + c * 512; }
        else if (c < 16) { g = XL  + (size_t)(row0 + (c - 8) * 16 + mrow) * DM + k0 + kcol;  l = Al + (c - 8) * 512; }
        else if (c < 20) { g = WTH + (size_t)(col0 + (c - 16) * 16 + mrow) * DM + k0 + kcol; l = Bh + (c - 16) * 512; }
        else             { g = WTL + (size_t)(col0 + (c - 20) * 16 + mrow) * DM + k0 + kcol; l = Bl + (c - 20) * 512; }
      } else {
        if (c < 8)       { g = XH  + (size_t)(row0 + c * 16 + mrow) * DM + k0 + kcol;        l = Ah + c * 512; }
        else             { g = WTH + (size_t)(col0 + (c - 8) * 16 + mrow) * DM + k0 + kcol;  l = Bh + (c - 8) * 512; }
      }
      gload16(l, g);
    }
    __syncthreads();

    short8 ah[4], bh[2];
#pragma unroll
    for (int i = 0; i < 4; i++) ah[i] = *(const short8*)&Ah[(wr + i * 16 + lr) * 32 + kb8];
#pragma unroll
    for (int j = 0; j < 2; j++) bh[j] = *(const short8*)&Bh[(wc + j * 16 + lr) * 32 + kb8];
    if constexpr (SPLIT3) {
      short8 al[4], bl[2];
#pragma unroll
      for (int i = 0; i < 4; i++) al[i] = *(const short8*)&Al[(wr + i * 16 + lr) * 32 + kb8];
#pragma unroll
      for (int j = 0; j < 2; j++) bl[j] = *(const short8*)&Bl[(wc + j * 16 + lr) * 32 + kb8];
#pragma unroll
      for (int i = 0; i < 4; i++)
#pragma unroll
        for (int j = 0; j < 2; j++) {
          acc[i][j] = __builtin_amdgcn_mfma_f32_16x16x32_bf16(ah[i], bh[j], acc[i][j], 0, 0, 0);
          acc[i][j] = __builtin_amdgcn_mfma_f32_16x16x32_bf16(ah[i], bl[j], acc[i][j], 0, 0, 0);
          acc[i][j] = __builtin_amdgcn_mfma_f32_16x16x32_bf16(al[i], bh[j], acc[i][j], 0, 0, 0);
        }
    } else {
#pragma unroll
      for (int i = 0; i < 4; i++)
#pragma unroll
        for (int j = 0; j < 2; j++)
          acc[i][j] = __builtin_amdgcn_mfma_f32_16x16x32_bf16(ah[i], bh[j], acc[i][j], 0, 0, 0);
    }
  }

  // epilogue: D layout col=lane&15, row=(lane>>4)*4+r
#pragma unroll
  for (int i = 0; i < 4; i++)
#pragma unroll
    for (int j = 0; j < 2; j++) {
      const int col = col0 + wc + j * 16 + lr;
      const float bval = bias[col];
#pragma unroll
      for (int r = 0; r < 4; r++) {
        const int row = row0 + wr + i * 16 + (lane >> 4) * 4 + r;
        const float v = acc[i][j][r] + bval;
        if constexpr (TOSPLIT) {
          const int b = row >> 11, l2 = row & (SEQ - 1);
          const int h = col >> 6, dk = col & 63;
          out[((size_t)(b * NH + h) * SEQ + l2) * DH + dk] = v;
        } else {
          out[(size_t)row * DM + col] = v;
        }
      }
    }
}

// ---------------------------------------------------------------------------
// M[b,h,q] = max_j(Q[bhq]·K[bh,idx[q,j]]) - sum_j(...)/SEQ.  One wave per row.
// ---------------------------------------------------------------------------
__global__ __launch_bounds__(256) void m_kernel(const float* __restrict__ Q,
                                                const float* __restrict__ K,
                                                const int* __restrict__ idxs,
                                                float* __restrict__ M) {
  const int lane = threadIdx.x & 63;
  const int r = blockIdx.x * 4 + (threadIdx.x >> 6);  // [0, BHROWS)
  const int q = r & (SEQ - 1);
  const int g = lane >> 3;        // sample group 0..7
  const int d8 = (lane & 7) * 8;  // dim slice start
  const float* Qr = Q + (size_t)r * DH + d8;
  const float4 q0 = *(const float4*)Qr;
  const float4 q1 = *(const float4*)(Qr + 4);
  const float* Kbh = K + (size_t)(r >> 11) * SEQ * DH;

  int ks[5];
#pragma unroll
  for (int p = 0; p < 5; p++) ks[p] = idxs[q * NS + g + 8 * p];
  float4 k0[5], k1[5];
#pragma unroll
  for (int p = 0; p < 5; p++) {
    const float* Kr = Kbh + (size_t)ks[p] * DH + d8;
    k0[p] = *(const float4*)Kr;
    k1[p] = *(const float4*)(Kr + 4);
  }
  float mx = -1e30f, sm = 0.f;
#pragma unroll
  for (int p = 0; p < 5; p++) {
    float acc = q0.x * k0[p].x + q0.y * k0[p].y + q0.z * k0[p].z + q0.w * k0[p].w +
                q1.x * k1[p].x + q1.y * k1[p].y + q1.z * k1[p].z + q1.w * k1[p].w;
    acc += __shfl_xor(acc, 1, 64);
    acc += __shfl_xor(acc, 2, 64);
    acc += __shfl_xor(acc, 4, 64);
    mx = fmaxf(mx, acc);
    sm += acc;
  }
#pragma unroll
  for (int o = 8; o <= 32; o <<= 1) {
    mx = fmaxf(mx, __shfl_xor(mx, o, 64));
    sm += __shfl_xor(sm, o, 64);
  }
  if (lane == 0) M[r] = mx - sm * (1.0f / (float)SEQ);
}

// ---------------------------------------------------------------------------
// Top-40 of M per (b,h) via full bitonic sort of packed u64 keys in LDS.
// One block of 1024 threads (16 waves) per (b,h) — latency hidden by TLP.
// key = ordered(float)<<32 | ~idx: descending key order == jax top_k order
// (value desc, index asc on ties). Take first NT after sort.
// ---------------------------------------------------------------------------
__global__ __launch_bounds__(1024) void topk_kernel(const float* __restrict__ M,
                                                    int* __restrict__ Mtop) {
  __shared__ u64 keys[SEQ];   // 16 KB
  const int bh = blockIdx.x, tid = threadIdx.x;
  const float* Mb = M + (size_t)bh * SEQ;
#pragma unroll
  for (int i = tid; i < SEQ; i += 1024) {
    unsigned ub = __float_as_uint(Mb[i]);
    ub ^= (ub >> 31) ? 0xFFFFFFFFu : 0x80000000u;      // order-preserving map
    keys[i] = ((u64)ub << 32) | (u64)(unsigned)~i;     // lower idx -> larger key
  }
  __syncthreads();
  for (int k = 2; k <= SEQ; k <<= 1) {
    for (int j = k >> 1; j > 0; j >>= 1) {
#pragma unroll
      for (int i = tid; i < SEQ; i += 1024) {
        const int partner = i ^ j;
        if (partner > i) {
          const u64 a = keys[i], b = keys[partner];
          const bool desc = ((i & k) == 0);
          if (desc ? (a < b) : (a > b)) { keys[i] = b; keys[partner] = a; }
        }
      }
      __syncthreads();
    }
  }
  if (tid < NT) Mtop[bh * NT + tid] = (int)~(unsigned)keys[tid];
}

// ---------------------------------------------------------------------------
// V_sum stage 1: partial[bh][c][dk] = sum of 128 rows. Grid (32, 16).
// ---------------------------------------------------------------------------
__global__ __launch_bounds__(256) void vsum1_kernel(const float* __restrict__ V,
                                                    float* __restrict__ part) {
  __shared__ float sm[4][DH];
  const int bh = blockIdx.x, c = blockIdx.y, tid = threadIdx.x;
  const int dk = tid & 63, p = tid >> 6;
  const float* Vb = V + ((size_t)bh * SEQ + c * (SEQ / VCH)) * DH;
  float s = 0.f;
  for (int l = p; l < SEQ / VCH; l += 4) s += Vb[(size_t)l * DH + dk];
  sm[p][dk] = s;
  __syncthreads();
  if (p == 0)
    part[(size_t)(bh * VCH + c) * DH + dk] = sm[0][dk] + sm[1][dk] + sm[2][dk] + sm[3][dk];
}

__global__ __launch_bounds__(64) void vsum2_kernel(const float* __restrict__ part,
                                                   float* __restrict__ Vsum) {
  const int bh = blockIdx.x, dk = threadIdx.x;
  float s = 0.f;
#pragma unroll
  for (int c = 0; c < VCH; c++) s += part[(size_t)(bh * VCH + c) * DH + dk];
  Vsum[bh * DH + dk] = s;
}

// ---------------------------------------------------------------------------
// ctxT (B,L,D): V_sum broadcast (selected rows overwritten by reduce_scatter).
// ---------------------------------------------------------------------------
__global__ __launch_bounds__(256) void ctxinit_kernel(const float* __restrict__ Vsum,
                                                      float* __restrict__ ctxT) {
  const int idx = blockIdx.x * 256 + threadIdx.x;  // float4 index
  const int f = idx * 4;
  const int d = f & (DM - 1), b = f >> 20;
  float4 v = *(const float4*)&Vsum[b * DM + d];
  *(float4*)&ctxT[f] = v;
}

// ---------------------------------------------------------------------------
// scores[bh,u,s] = (Q[bh,Mtop[u]] · K[bh,s]) / 8.  Block: (bh, s-chunk of 256).
// ---------------------------------------------------------------------------
__global__ __launch_bounds__(256) void scores_kernel(const float* __restrict__ Q,
                                                     const float* __restrict__ K,
                                                     const int* __restrict__ Mtop,
                                                     float* __restrict__ scores) {
  __shared__ float Qs[NT * DH];
  const int bh = blockIdx.x, tid = threadIdx.x;
  for (int i = tid; i < NT * DH; i += 256) {
    int u = i >> 6, dk = i & 63;
    int row = Mtop[bh * NT + u];
    Qs[i] = Q[((size_t)bh * SEQ + row) * DH + dk];
  }
  __syncthreads();
  const int s = blockIdx.y * 256 + tid;
  const float* Krow = K + ((size_t)bh * SEQ + s) * DH;
  float4 kr[16];
#pragma unroll
  for (int g = 0; g < 16; g++) kr[g] = *(const float4*)&Krow[g * 4];
  for (int u = 0; u < NT; u++) {
    float acc = 0.f;
#pragma unroll
    for (int g = 0; g < 16; g++) {
      float4 qv = *(const float4*)&Qs[u * DH + g * 4];
      acc = fmaf(qv.x, kr[g].x, acc);
      acc = fmaf(qv.y, kr[g].y, acc);
      acc = fmaf(qv.z, kr[g].z, acc);
      acc = fmaf(qv.w, kr[g].w, acc);
    }
    scores[((size_t)bh * NT + u) * SEQ + s] = acc * 0.125f;
  }
}

// ---------------------------------------------------------------------------
// Row softmax over 2048, in place. One block per (bh,u) row.
// ---------------------------------------------------------------------------
__global__ __launch_bounds__(256) void softmax_kernel(float* __restrict__ scores) {
  __shared__ float red[256];
  const int row = blockIdx.x, tid = threadIdx.x;
  float* p = scores + (size_t)row * SEQ;
  float4 v0 = *(const float4*)&p[tid * 4];
  float4 v1 = *(const float4*)&p[1024 + tid * 4];
  float mx = fmaxf(fmaxf(fmaxf(v0.x, v0.y), fmaxf(v0.z, v0.w)),
                   fmaxf(fmaxf(v1.x, v1.y), fmaxf(v1.z, v1.w)));
  red[tid] = mx;
  __syncthreads();
  for (int s = 128; s; s >>= 1) {
    if (tid < s) red[tid] = fmaxf(red[tid], red[tid + s]);
    __syncthreads();
  }
  mx = red[0];
  __syncthreads();
  v0.x = __expf(v0.x - mx); v0.y = __expf(v0.y - mx);
  v0.z = __expf(v0.z - mx); v0.w = __expf(v0.w - mx);
  v1.x = __expf(v1.x - mx); v1.y = __expf(v1.y - mx);
  v1.z = __expf(v1.z - mx); v1.w = __expf(v1.w - mx);
  float sm = v0.x + v0.y + v0.z + v0.w + v1.x + v1.y + v1.z + v1.w;
  red[tid] = sm;
  __syncthreads();
  for (int s = 128; s; s >>= 1) {
    if (tid < s) red[tid] += red[tid + s];
    __syncthreads();
  }
  float inv = 1.0f / red[0];
  v0.x *= inv; v0.y *= inv; v0.z *= inv; v0.w *= inv;
  v1.x *= inv; v1.y *= inv; v1.z *= inv; v1.w *= inv;
  *(float4*)&p[tid * 4] = v0;
  *(float4*)&p[1024 + tid * 4] = v1;
}

// ---------------------------------------------------------------------------
// Partial upd = attn @ V over one 256-wide s-chunk. No atomics.
// ---------------------------------------------------------------------------
__global__ __launch_bounds__(256) void pv_partial_kernel(const float* __restrict__ attn,
                                                         const float* __restrict__ V,
                                                         float* __restrict__ updp) {
  __shared__ float Vl[64 * DH];
  __shared__ float Al2[NT * 64];
  const int bh = blockIdx.x, sc = blockIdx.y, tid = threadIdx.x;
  const int s0 = sc * 256;
  const int wid = tid >> 6, dk = tid & 63;
  float acc[10] = {};

  for (int st = 0; st < 4; st++) {
    const int sb = s0 + st * 64;
    __syncthreads();
#pragma unroll
    for (int i = 0; i < 16; i++) {
      int idx = tid + i * 256;
      int sj = idx >> 6, d2 = idx & 63;
      Vl[idx] = V[((size_t)bh * SEQ + sb + sj) * DH + d2];
    }
#pragma unroll
    for (int i = 0; i < 10; i++) {
      int idx = tid + i * 256;
      int u = idx >> 6, sj = idx & 63;
      Al2[idx] = attn[((size_t)bh * NT + u) * SEQ + sb + sj];
    }
    __syncthreads();
    for (int g = 0; g < 16; g++) {
      float a[10][4];
#pragma unroll
      for (int i = 0; i < 10; i++) {
        float4 t = *(const float4*)&Al2[(wid + 4 * i) * 64 + g * 4];
        a[i][0] = t.x; a[i][1] = t.y; a[i][2] = t.z; a[i][3] = t.w;
      }
#pragma unroll
      for (int t = 0; t < 4; t++) {
        float v = Vl[(g * 4 + t) * DH + dk];
#pragma unroll
        for (int i = 0; i < 10; i++) acc[i] = fmaf(a[i][t], v, acc[i]);
      }
    }
  }

#pragma unroll
  for (int i = 0; i < 10; i++) {
    int u = wid + 4 * i;
    updp[((size_t)(bh * NSC + sc) * NT + u) * DH + dk] = acc[i];
  }
}

// ---------------------------------------------------------------------------
// Sum the NSC partials in fixed order, overwrite selected ctxT rows.
// ---------------------------------------------------------------------------
__global__ __launch_bounds__(256) void reduce_scatter_kernel(const float* __restrict__ updp,
                                                             const int* __restrict__ Mtop,
                                                             float* __restrict__ ctxT) {
  const int bh = blockIdx.x;
  const int u = blockIdx.y * 4 + (threadIdx.x >> 6);
  const int dk = threadIdx.x & 63;
  float s = 0.f;
#pragma unroll
  for (int sc = 0; sc < NSC; sc++)
    s += updp[((size_t)(bh * NSC + sc) * NT + u) * DH + dk];
  const int row = Mtop[bh * NT + u];
  const int b = bh >> 3, h = bh & 7;
  ctxT[((size_t)b * SEQ + row) * DM + h * DH + dk] = s;
}

// ---------------------------------------------------------------------------
extern "C" void kernel_launch(void* const* d_in, const int* in_sizes, int n_in,
                              void* d_out, int out_size, void* d_ws, size_t ws_size,
                              hipStream_t stream) {
  (void)in_sizes; (void)n_in; (void)out_size; (void)ws_size;
  const float* queries = (const float*)d_in[0];
  const float* keys    = (const float*)d_in[1];
  const float* values  = (const float*)d_in[2];
  const int* index_sample = (const int*)d_in[4];
  const float* Wq = (const float*)d_in[5];
  const float* bq = (const float*)d_in[6];
  const float* Wk = (const float*)d_in[7];
  const float* bk = (const float*)d_in[8];
  const float* Wv = (const float*)d_in[9];
  const float* bv = (const float*)d_in[10];
  const float* Wo = (const float*)d_in[11];
  const float* bo = (const float*)d_in[12];
  float* out = (float*)d_out;

  // ws (floats): Q,Kp,Vp,ctxT 4x 4,194,304; scores 2,621,440; M 65,536;
  // Vsum 2,048; vpart 32,768; Mtop ints  => ~78 MB (same as round 7).
  float* ws = (float*)d_ws;
  float* Q    = ws;
  float* Kp   = Q + (size_t)ROWS * DM;
  float* Vp   = Kp + (size_t)ROWS * DM;
  float* ctxT = Vp + (size_t)ROWS * DM;
  float* scores = ctxT + (size_t)ROWS * DM;
  float* M    = scores + (size_t)NB * NH * NT * SEQ;
  float* Vsum = M + BHROWS;
  float* vpart = Vsum + NB * NH * DH;
  int* Mtop   = (int*)(vpart + NB * NH * VCH * DH);
  float* updp = Q;

  u16* XH = (u16*)ctxT;
  u16* XL = XH + (size_t)ROWS * DM;
  u16* WH = (u16*)scores;
  u16* WL = WH + (size_t)DM * DM;
  u16* CH  = (u16*)scores;
  u16* WoH = CH + (size_t)ROWS * DM;

  const int n4x = ROWS * DM / 4;          // 1,048,576 float4s
  const dim3 gG(ROWS / 128, DM / 64);     // (64, 8)
  const dim3 gW(8, 8);

  // Q projection (split-bf16 3-pass)
  cvt_split_kernel<<<n4x / 256, 256, 0, stream>>>(queries, XH, XL, 1);
  cvt_wt_kernel<<<gW, 256, 0, stream>>>(Wq, WH, WL, 1);
  gemm_mfma<true, true><<<gG, 256, 0, stream>>>(XH, XL, WH, WL, bq, Q);
  // K projection (split-bf16 3-pass)
  cvt_split_kernel<<<n4x / 256, 256, 0, stream>>>(keys, XH, XL, 1);
  cvt_wt_kernel<<<gW, 256, 0, stream>>>(Wk, WH, WL, 1);
  gemm_mfma<true, true><<<gG, 256, 0, stream>>>(XH, XL, WH, WL, bk, Kp);
  // V projection (single-pass bf16)
  cvt_split_kernel<<<n4x / 256, 256, 0, stream>>>(values, XH, XL, 0);
  cvt_wt_kernel<<<gW, 256, 0, stream>>>(Wv, WH, WL, 0);
  gemm_mfma<false, true><<<gG, 256, 0, stream>>>(XH, XH, WH, WH, bv, Vp);

  m_kernel<<<BHROWS / 4, 256, 0, stream>>>(Q, Kp, index_sample, M);
  topk_kernel<<<NB * NH, 1024, 0, stream>>>(M, Mtop);
  vsum1_kernel<<<dim3(NB * NH, VCH), 256, 0, stream>>>(Vp, vpart);
  vsum2_kernel<<<NB * NH, 64, 0, stream>>>(vpart, Vsum);
  ctxinit_kernel<<<(ROWS * DM / 4) / 256, 256, 0, stream>>>(Vsum, ctxT);
  scores_kernel<<<dim3(NB * NH, SEQ / 256), 256, 0, stream>>>(Q, Kp, Mtop, scores);
  softmax_kernel<<<NB * NH * NT, 256, 0, stream>>>(scores);
  pv_partial_kernel<<<dim3(NB * NH, NSC), 256, 0, stream>>>(scores, Vp, updp);
  reduce_scatter_kernel<<<dim3(NB * NH, NT / 4), 256, 0, stream>>>(updp, Mtop, ctxT);

  // Output projection (single-pass bf16)
  cvt_split_kernel<<<n4x / 256, 256, 0, stream>>>(ctxT, CH, CH, 0);
  cvt_wt_kernel<<<gW, 256, 0, stream>>>(Wo, WoH, WoH, 0);
  gemm_mfma<false, false><<<gG, 256, 0, stream>>>(CH, CH, WoH, WoH, bo, out);
}

// Round 9
// 233.501 us; speedup vs baseline: 2.7803x; 1.0299x over previous
//
#include <hip/hip_runtime.h>

// ProbSparse attention (Informer) — B=4, L=2048, D=512, H=8, DK=64, SK=NTOP=40
// Round 9: m_kernel — idx staged via LDS (kills the idx->K dependent global
// round-trip) + bijective XCD-aware block swizzle (each XCD owns 4 bh K-slices
// = 2MB < 4MB L2 -> sampled K reads become L2-resident).
// Everything else unchanged from R8.

typedef unsigned short u16;
typedef unsigned long long u64;
typedef __attribute__((ext_vector_type(8))) short short8;
typedef __attribute__((ext_vector_type(4))) float f32x4;

constexpr int NB = 4;       // batch
constexpr int SEQ = 2048;   // L
constexpr int DM = 512;     // D
constexpr int NH = 8;
constexpr int DH = 64;      // DK
constexpr int NS = 40;      // SK (samples)
constexpr int NT = 40;      // NTOP
constexpr int ROWS = NB * SEQ;          // 8192
constexpr int BHROWS = NB * NH * SEQ;   // 65536
constexpr int NSC = 8;      // s-chunks in pv (SEQ/256)
constexpr int VCH = 16;     // vsum l-chunks per (b,h)

// ---------------------------------------------------------------------------
// bf16 helpers (round-to-nearest-even)
// ---------------------------------------------------------------------------
__device__ __forceinline__ u16 f2bf(float x) {
  union { float f; unsigned u; } v; v.f = x;
  unsigned r = v.u + 0x7FFFu + ((v.u >> 16) & 1u);
  return (u16)(r >> 16);
}
__device__ __forceinline__ float bf2f(u16 b) {
  union { unsigned u; float f; } v; v.u = ((unsigned)b) << 16;
  return v.f;
}

__device__ __forceinline__ void gload16(void* lds, const void* g) {
  __builtin_amdgcn_global_load_lds(
      (const __attribute__((address_space(1))) unsigned int*)g,
      (__attribute__((address_space(3))) unsigned int*)lds, 16, 0, 0);
}

// ---------------------------------------------------------------------------
// X (R x 512 fp32, row-major) -> H (+L) bf16, same layout. One float4/thread.
// ---------------------------------------------------------------------------
__global__ __launch_bounds__(256) void cvt_split_kernel(const float* __restrict__ X,
                                                        u16* __restrict__ H,
                                                        u16* __restrict__ L,
                                                        int doLo) {
  const int i = blockIdx.x * 256 + threadIdx.x;
  float4 v = ((const float4*)X)[i];
  ushort4 h;
  h.x = f2bf(v.x); h.y = f2bf(v.y); h.z = f2bf(v.z); h.w = f2bf(v.w);
  ((ushort4*)H)[i] = h;
  if (doLo) {
    ushort4 l;
    l.x = f2bf(v.x - bf2f(h.x)); l.y = f2bf(v.y - bf2f(h.y));
    l.z = f2bf(v.z - bf2f(h.z)); l.w = f2bf(v.w - bf2f(h.w));
    ((ushort4*)L)[i] = l;
  }
}

// ---------------------------------------------------------------------------
// W (512x512 fp32, [k][n]) -> Wt bf16 [n][k] hi (+lo). 64x64 tiles, grid (8,8).
// ---------------------------------------------------------------------------
__global__ __launch_bounds__(256) void cvt_wt_kernel(const float* __restrict__ W,
                                                     u16* __restrict__ H,
                                                     u16* __restrict__ L,
                                                     int doLo) {
  __shared__ float T[64][65];
  const int c0 = blockIdx.x * 64;  // n
  const int r0 = blockIdx.y * 64;  // k
  const int t = threadIdx.x;
  const int lr = t >> 4, lc4 = (t & 15) * 4;
#pragma unroll
  for (int i = 0; i < 4; i++) {
    float4 v = *(const float4*)&W[(size_t)(r0 + lr + i * 16) * DM + c0 + lc4];
    T[lr + i * 16][lc4 + 0] = v.x;
    T[lr + i * 16][lc4 + 1] = v.y;
    T[lr + i * 16][lc4 + 2] = v.z;
    T[lr + i * 16][lc4 + 3] = v.w;
  }
  __syncthreads();
#pragma unroll
  for (int i = 0; i < 4; i++) {
    const int n = lr + i * 16;
    float x0 = T[lc4 + 0][n], x1 = T[lc4 + 1][n], x2 = T[lc4 + 2][n], x3 = T[lc4 + 3][n];
    ushort4 h;
    h.x = f2bf(x0); h.y = f2bf(x1); h.z = f2bf(x2); h.w = f2bf(x3);
    *(ushort4*)&H[(size_t)(c0 + n) * DM + r0 + lc4] = h;
    if (doLo) {
      ushort4 l;
      l.x = f2bf(x0 - bf2f(h.x)); l.y = f2bf(x1 - bf2f(h.y));
      l.z = f2bf(x2 - bf2f(h.z)); l.w = f2bf(x3 - bf2f(h.w));
      *(ushort4*)&L[(size_t)(c0 + n) * DM + r0 + lc4] = l;
    }
  }
}

// ---------------------------------------------------------------------------
// MFMA GEMM: C(8192x512) = X(8192x512) @ W(512x512) + bias, bf16 inputs.
// 128(M) x 64(N) tile, BK=32, 256 thr, 4 waves (2x2), wave tile 64x32.
// SPLIT3: 3-pass split-bf16 (Ah*Bh + Ah*Bl + Al*Bh). TOSPLIT: (B,H,L,DH) out.
// ---------------------------------------------------------------------------
template <bool SPLIT3, bool TOSPLIT>
__global__ __launch_bounds__(256) void gemm_mfma(const u16* __restrict__ XH,
                                                 const u16* __restrict__ XL,
                                                 const u16* __restrict__ WTH,
                                                 const u16* __restrict__ WTL,
                                                 const float* __restrict__ bias,
                                                 float* __restrict__ out) {
  __shared__ __align__(16) u16 Ah[128 * 32];
  __shared__ __align__(16) u16 Al[128 * 32];
  __shared__ __align__(16) u16 Bh[64 * 32];
  __shared__ __align__(16) u16 Bl[64 * 32];
  const int tid = threadIdx.x, lane = tid & 63, w = tid >> 6;
  const int row0 = blockIdx.x * 128, col0 = blockIdx.y * 64;
  const int wr = (w >> 1) * 64, wc = (w & 1) * 32;
  const int lr = lane & 15, kb8 = (lane >> 4) * 8;
  const int mrow = lane >> 2;          // row within 16-row chunk
  const int kcol = (lane & 3) * 8;     // bf16 elements into the 32-wide k slab

  f32x4 acc[4][2];
#pragma unroll
  for (int i = 0; i < 4; i++)
#pragma unroll
    for (int j = 0; j < 2; j++) acc[i][j] = (f32x4){0.f, 0.f, 0.f, 0.f};

  constexpr int PER = SPLIT3 ? 6 : 3;  // staging chunks per wave

  for (int k0 = 0; k0 < DM; k0 += 32) {
    __syncthreads();
#pragma unroll
    for (int i = 0; i < PER; i++) {
      const int c = w * PER + i;
      const u16* g;
      u16* l;
      if (SPLIT3) {
        if (c < 8)       { g = XH  + (size_t)(row0 + c * 16 + mrow) * DM + k0 + kcol;        l = Ah + c * 512; }
        else if (c < 16) { g = XL  + (size_t)(row0 + (c - 8) * 16 + mrow) * DM + k0 + kcol;  l = Al + (c - 8) * 512; }
        else if (c < 20) { g = WTH + (size_t)(col0 + (c - 16) * 16 + mrow) * DM + k0 + kcol; l = Bh + (c - 16) * 512; }
        else             { g = WTL + (size_t)(col0 + (c - 20) * 16 + mrow) * DM + k0 + kcol; l = Bl + (c - 20) * 512; }
      } else {
        if (c < 8)       { g = XH  + (size_t)(row0 + c * 16 + mrow) * DM + k0 + kcol;        l = Ah + c * 512; }
        else             { g = WTH + (size_t)(col0 + (c - 8) * 16 + mrow) * DM + k0 + kcol;  l = Bh + (c - 8) * 512; }
      }
      gload16(l, g);
    }
    __syncthreads();

    short8 ah[4], bh[2];
#pragma unroll
    for (int i = 0; i < 4; i++) ah[i] = *(const short8*)&Ah[(wr + i * 16 + lr) * 32 + kb8];
#pragma unroll
    for (int j = 0; j < 2; j++) bh[j] = *(const short8*)&Bh[(wc + j * 16 + lr) * 32 + kb8];
    if constexpr (SPLIT3) {
      short8 al[4], bl[2];
#pragma unroll
      for (int i = 0; i < 4; i++) al[i] = *(const short8*)&Al[(wr + i * 16 + lr) * 32 + kb8];
#pragma unroll
      for (int j = 0; j < 2; j++) bl[j] = *(const short8*)&Bl[(wc + j * 16 + lr) * 32 + kb8];
#pragma unroll
      for (int i = 0; i < 4; i++)
#pragma unroll
        for (int j = 0; j < 2; j++) {
          acc[i][j] = __builtin_amdgcn_mfma_f32_16x16x32_bf16(ah[i], bh[j], acc[i][j], 0, 0, 0);
          acc[i][j] = __builtin_amdgcn_mfma_f32_16x16x32_bf16(ah[i], bl[j], acc[i][j], 0, 0, 0);
          acc[i][j] = __builtin_amdgcn_mfma_f32_16x16x32_bf16(al[i], bh[j], acc[i][j], 0, 0, 0);
        }
    } else {
#pragma unroll
      for (int i = 0; i < 4; i++)
#pragma unroll
        for (int j = 0; j < 2; j++)
          acc[i][j] = __builtin_amdgcn_mfma_f32_16x16x32_bf16(ah[i], bh[j], acc[i][j], 0, 0, 0);
    }
  }

  // epilogue: D layout col=lane&15, row=(lane>>4)*4+r
#pragma unroll
  for (int i = 0; i < 4; i++)
#pragma unroll
    for (int j = 0; j < 2; j++) {
      const int col = col0 + wc + j * 16 + lr;
      const float bval = bias[col];
#pragma unroll
      for (int r = 0; r < 4; r++) {
        const int row = row0 + wr + i * 16 + (lane >> 4) * 4 + r;
        const float v = acc[i][j][r] + bval;
        if constexpr (TOSPLIT) {
          const int b = row >> 11, l2 = row & (SEQ - 1);
          const int h = col >> 6, dk = col & 63;
          out[((size_t)(b * NH + h) * SEQ + l2) * DH + dk] = v;
        } else {
          out[(size_t)row * DM + col] = v;
        }
      }
    }
}

// ---------------------------------------------------------------------------
// M[b,h,q] = max_j(Q[bhq]·K[bh,idx[q,j]]) - sum_j(...)/SEQ.  One wave per row.
// XCD-swizzled blocks: XCD x owns bh in [4x,4x+4) -> K slices L2-resident.
// idx staged in LDS (one coalesced load) -> single global round-trip for K.
// ---------------------------------------------------------------------------
__global__ __launch_bounds__(256) void m_kernel(const float* __restrict__ Q,
                                                const float* __restrict__ K,
                                                const int* __restrict__ idxs,
                                                float* __restrict__ M) {
  __shared__ int idl[4 * NS];
  const int tid = threadIdx.x;
  // bijective swizzle: blocks with bid%8==x all map to bh in [4x, 4x+4)
  const int x = blockIdx.x & 7;        // XCD (HW round-robins on bid%8)
  const int slot = blockIdx.x >> 3;    // 0..2047
  const int bh = x * 4 + (slot >> 9);  // 4 bh-slices per XCD (2MB K < 4MB L2)
  const int q4 = slot & 511;           // q-block within bh
  const int q0 = q4 * 4;

  if (tid < 4 * NS) idl[tid] = idxs[q0 * NS + tid];
  __syncthreads();

  const int lane = tid & 63, wid = tid >> 6;
  const int r = bh * SEQ + q0 + wid;
  const int g = lane >> 3;        // sample group 0..7
  const int d8 = (lane & 7) * 8;  // dim slice start
  const float* Qr = Q + (size_t)r * DH + d8;
  const float4 q0v = *(const float4*)Qr;
  const float4 q1v = *(const float4*)(Qr + 4);
  const float* Kbh = K + (size_t)bh * SEQ * DH;

  int ks[5];
#pragma unroll
  for (int p = 0; p < 5; p++) ks[p] = idl[wid * NS + g + 8 * p];
  float4 k0[5], k1[5];
#pragma unroll
  for (int p = 0; p < 5; p++) {
    const float* Kr = Kbh + (size_t)ks[p] * DH + d8;
    k0[p] = *(const float4*)Kr;
    k1[p] = *(const float4*)(Kr + 4);
  }
  float mx = -1e30f, sm = 0.f;
#pragma unroll
  for (int p = 0; p < 5; p++) {
    float acc = q0v.x * k0[p].x + q0v.y * k0[p].y + q0v.z * k0[p].z + q0v.w * k0[p].w +
                q1v.x * k1[p].x + q1v.y * k1[p].y + q1v.z * k1[p].z + q1v.w * k1[p].w;
    acc += __shfl_xor(acc, 1, 64);
    acc += __shfl_xor(acc, 2, 64);
    acc += __shfl_xor(acc, 4, 64);
    mx = fmaxf(mx, acc);
    sm += acc;
  }
#pragma unroll
  for (int o = 8; o <= 32; o <<= 1) {
    mx = fmaxf(mx, __shfl_xor(mx, o, 64));
    sm += __shfl_xor(sm, o, 64);
  }
  if (lane == 0) M[r] = mx - sm * (1.0f / (float)SEQ);
}

// ---------------------------------------------------------------------------
// Top-40 of M per (b,h) via full bitonic sort of packed u64 keys in LDS.
// One block of 1024 threads (16 waves) per (b,h).
// key = ordered(float)<<32 | ~idx: descending key order == jax top_k order.
// ---------------------------------------------------------------------------
__global__ __launch_bounds__(1024) void topk_kernel(const float* __restrict__ M,
                                                    int* __restrict__ Mtop) {
  __shared__ u64 keys[SEQ];   // 16 KB
  const int bh = blockIdx.x, tid = threadIdx.x;
  const float* Mb = M + (size_t)bh * SEQ;
#pragma unroll
  for (int i = tid; i < SEQ; i += 1024) {
    unsigned ub = __float_as_uint(Mb[i]);
    ub ^= (ub >> 31) ? 0xFFFFFFFFu : 0x80000000u;      // order-preserving map
    keys[i] = ((u64)ub << 32) | (u64)(unsigned)~i;     // lower idx -> larger key
  }
  __syncthreads();
  for (int k = 2; k <= SEQ; k <<= 1) {
    for (int j = k >> 1; j > 0; j >>= 1) {
#pragma unroll
      for (int i = tid; i < SEQ; i += 1024) {
        const int partner = i ^ j;
        if (partner > i) {
          const u64 a = keys[i], b = keys[partner];
          const bool desc = ((i & k) == 0);
          if (desc ? (a < b) : (a > b)) { keys[i] = b; keys[partner] = a; }
        }
      }
      __syncthreads();
    }
  }
  if (tid < NT) Mtop[bh * NT + tid] = (int)~(unsigned)keys[tid];
}

// ---------------------------------------------------------------------------
// V_sum stage 1: partial[bh][c][dk] = sum of 128 rows. Grid (32, 16).
// ---------------------------------------------------------------------------
__global__ __launch_bounds__(256) void vsum1_kernel(const float* __restrict__ V,
                                                    float* __restrict__ part) {
  __shared__ float sm[4][DH];
  const int bh = blockIdx.x, c = blockIdx.y, tid = threadIdx.x;
  const int dk = tid & 63, p = tid >> 6;
  const float* Vb = V + ((size_t)bh * SEQ + c * (SEQ / VCH)) * DH;
  float s = 0.f;
  for (int l = p; l < SEQ / VCH; l += 4) s += Vb[(size_t)l * DH + dk];
  sm[p][dk] = s;
  __syncthreads();
  if (p == 0)
    part[(size_t)(bh * VCH + c) * DH + dk] = sm[0][dk] + sm[1][dk] + sm[2][dk] + sm[3][dk];
}

__global__ __launch_bounds__(64) void vsum2_kernel(const float* __restrict__ part,
                                                   float* __restrict__ Vsum) {
  const int bh = blockIdx.x, dk = threadIdx.x;
  float s = 0.f;
#pragma unroll
  for (int c = 0; c < VCH; c++) s += part[(size_t)(bh * VCH + c) * DH + dk];
  Vsum[bh * DH + dk] = s;
}

// ---------------------------------------------------------------------------
// ctxT (B,L,D): V_sum broadcast (selected rows overwritten by reduce_scatter).
// ---------------------------------------------------------------------------
__global__ __launch_bounds__(256) void ctxinit_kernel(const float* __restrict__ Vsum,
                                                      float* __restrict__ ctxT) {
  const int idx = blockIdx.x * 256 + threadIdx.x;  // float4 index
  const int f = idx * 4;
  const int d = f & (DM - 1), b = f >> 20;
  float4 v = *(const float4*)&Vsum[b * DM + d];
  *(float4*)&ctxT[f] = v;
}

// ---------------------------------------------------------------------------
// scores[bh,u,s] = (Q[bh,Mtop[u]] · K[bh,s]) / 8.  Block: (bh, s-chunk of 256).
// ---------------------------------------------------------------------------
__global__ __launch_bounds__(256) void scores_kernel(const float* __restrict__ Q,
                                                     const float* __restrict__ K,
                                                     const int* __restrict__ Mtop,
                                                     float* __restrict__ scores) {
  __shared__ float Qs[NT * DH];
  const int bh = blockIdx.x, tid = threadIdx.x;
  for (int i = tid; i < NT * DH; i += 256) {
    int u = i >> 6, dk = i & 63;
    int row = Mtop[bh * NT + u];
    Qs[i] = Q[((size_t)bh * SEQ + row) * DH + dk];
  }
  __syncthreads();
  const int s = blockIdx.y * 256 + tid;
  const float* Krow = K + ((size_t)bh * SEQ + s) * DH;
  float4 kr[16];
#pragma unroll
  for (int g = 0; g < 16; g++) kr[g] = *(const float4*)&Krow[g * 4];
  for (int u = 0; u < NT; u++) {
    float acc = 0.f;
#pragma unroll
    for (int g = 0; g < 16; g++) {
      float4 qv = *(const float4*)&Qs[u * DH + g * 4];
      acc = fmaf(qv.x, kr[g].x, acc);
      acc = fmaf(qv.y, kr[g].y, acc);
      acc = fmaf(qv.z, kr[g].z, acc);
      acc = fmaf(qv.w, kr[g].w, acc);
    }
    scores[((size_t)bh * NT + u) * SEQ + s] = acc * 0.125f;
  }
}

// ---------------------------------------------------------------------------
// Row softmax over 2048, in place. One block per (bh,u) row.
// ---------------------------------------------------------------------------
__global__ __launch_bounds__(256) void softmax_kernel(float* __restrict__ scores) {
  __shared__ float red[256];
  const int row = blockIdx.x, tid = threadIdx.x;
  float* p = scores + (size_t)row * SEQ;
  float4 v0 = *(const float4*)&p[tid * 4];
  float4 v1 = *(const float4*)&p[1024 + tid * 4];
  float mx = fmaxf(fmaxf(fmaxf(v0.x, v0.y), fmaxf(v0.z, v0.w)),
                   fmaxf(fmaxf(v1.x, v1.y), fmaxf(v1.z, v1.w)));
  red[tid] = mx;
  __syncthreads();
  for (int s = 128; s; s >>= 1) {
    if (tid < s) red[tid] = fmaxf(red[tid], red[tid + s]);
    __syncthreads();
  }
  mx = red[0];
  __syncthreads();
  v0.x = __expf(v0.x - mx); v0.y = __expf(v0.y - mx);
  v0.z = __expf(v0.z - mx); v0.w = __expf(v0.w - mx);
  v1.x = __expf(v1.x - mx); v1.y = __expf(v1.y - mx);
  v1.z = __expf(v1.z - mx); v1.w = __expf(v1.w - mx);
  float sm = v0.x + v0.y + v0.z + v0.w + v1.x + v1.y + v1.z + v1.w;
  red[tid] = sm;
  __syncthreads();
  for (int s = 128; s; s >>= 1) {
    if (tid < s) red[tid] += red[tid + s];
    __syncthreads();
  }
  float inv = 1.0f / red[0];
  v0.x *= inv; v0.y *= inv; v0.z *= inv; v0.w *= inv;
  v1.x *= inv; v1.y *= inv; v1.z *= inv; v1.w *= inv;
  *(float4*)&p[tid * 4] = v0;
  *(float4*)&p[1024 + tid * 4] = v1;
}

// ---------------------------------------------------------------------------
// Partial upd = attn @ V over one 256-wide s-chunk. No atomics.
// ---------------------------------------------------------------------------
__global__ __launch_bounds__(256) void pv_partial_kernel(const float* __restrict__ attn,
                                                         const float* __restrict__ V,
                                                         float* __restrict__ updp) {
  __shared__ float Vl[64 * DH];
  __shared__ float Al2[NT * 64];
  const int bh = blockIdx.x, sc = blockIdx.y, tid = threadIdx.x;
  const int s0 = sc * 256;
  const int wid = tid >> 6, dk = tid & 63;
  float acc[10] = {};

  for (int st = 0; st < 4; st++) {
    const int sb = s0 + st * 64;
    __syncthreads();
#pragma unroll
    for (int i = 0; i < 16; i++) {
      int idx = tid + i * 256;
      int sj = idx >> 6, d2 = idx & 63;
      Vl[idx] = V[((size_t)bh * SEQ + sb + sj) * DH + d2];
    }
#pragma unroll
    for (int i = 0; i < 10; i++) {
      int idx = tid + i * 256;
      int u = idx >> 6, sj = idx & 63;
      Al2[idx] = attn[((size_t)bh * NT + u) * SEQ + sb + sj];
    }
    __syncthreads();
    for (int g = 0; g < 16; g++) {
      float a[10][4];
#pragma unroll
      for (int i = 0; i < 10; i++) {
        float4 t = *(const float4*)&Al2[(wid + 4 * i) * 64 + g * 4];
        a[i][0] = t.x; a[i][1] = t.y; a[i][2] = t.z; a[i][3] = t.w;
      }
#pragma unroll
      for (int t = 0; t < 4; t++) {
        float v = Vl[(g * 4 + t) * DH + dk];
#pragma unroll
        for (int i = 0; i < 10; i++) acc[i] = fmaf(a[i][t], v, acc[i]);
      }
    }
  }

#pragma unroll
  for (int i = 0; i < 10; i++) {
    int u = wid + 4 * i;
    updp[((size_t)(bh * NSC + sc) * NT + u) * DH + dk] = acc[i];
  }
}

// ---------------------------------------------------------------------------
// Sum the NSC partials in fixed order, overwrite selected ctxT rows.
// ---------------------------------------------------------------------------
__global__ __launch_bounds__(256) void reduce_scatter_kernel(const float* __restrict__ updp,
                                                             const int* __restrict__ Mtop,
                                                             float* __restrict__ ctxT) {
  const int bh = blockIdx.x;
  const int u = blockIdx.y * 4 + (threadIdx.x >> 6);
  const int dk = threadIdx.x & 63;
  float s = 0.f;
#pragma unroll
  for (int sc = 0; sc < NSC; sc++)
    s += updp[((size_t)(bh * NSC + sc) * NT + u) * DH + dk];
  const int row = Mtop[bh * NT + u];
  const int b = bh >> 3, h = bh & 7;
  ctxT[((size_t)b * SEQ + row) * DM + h * DH + dk] = s;
}

// ---------------------------------------------------------------------------
extern "C" void kernel_launch(void* const* d_in, const int* in_sizes, int n_in,
                              void* d_out, int out_size, void* d_ws, size_t ws_size,
                              hipStream_t stream) {
  (void)in_sizes; (void)n_in; (void)out_size; (void)ws_size;
  const float* queries = (const float*)d_in[0];
  const float* keys    = (const float*)d_in[1];
  const float* values  = (const float*)d_in[2];
  const int* index_sample = (const int*)d_in[4];
  const float* Wq = (const float*)d_in[5];
  const float* bq = (const float*)d_in[6];
  const float* Wk = (const float*)d_in[7];
  const float* bk = (const float*)d_in[8];
  const float* Wv = (const float*)d_in[9];
  const float* bv = (const float*)d_in[10];
  const float* Wo = (const float*)d_in[11];
  const float* bo = (const float*)d_in[12];
  float* out = (float*)d_out;

  // ws (floats): Q,Kp,Vp,ctxT 4x 4,194,304; scores 2,621,440; M 65,536;
  // Vsum 2,048; vpart 32,768; Mtop ints  => ~78 MB (same as round 8).
  float* ws = (float*)d_ws;
  float* Q    = ws;
  float* Kp   = Q + (size_t)ROWS * DM;
  float* Vp   = Kp + (size_t)ROWS * DM;
  float* ctxT = Vp + (size_t)ROWS * DM;
  float* scores = ctxT + (size_t)ROWS * DM;
  float* M    = scores + (size_t)NB * NH * NT * SEQ;
  float* Vsum = M + BHROWS;
  float* vpart = Vsum + NB * NH * DH;
  int* Mtop   = (int*)(vpart + NB * NH * VCH * DH);
  float* updp = Q;

  u16* XH = (u16*)ctxT;
  u16* XL = XH + (size_t)ROWS * DM;
  u16* WH = (u16*)scores;
  u16* WL = WH + (size_t)DM * DM;
  u16* CH  = (u16*)scores;
  u16* WoH = CH + (size_t)ROWS * DM;

  const int n4x = ROWS * DM / 4;          // 1,048,576 float4s
  const dim3 gG(ROWS / 128, DM / 64);     // (64, 8)
  const dim3 gW(8, 8);

  // Q projection (split-bf16 3-pass)
  cvt_split_kernel<<<n4x / 256, 256, 0, stream>>>(queries, XH, XL, 1);
  cvt_wt_kernel<<<gW, 256, 0, stream>>>(Wq, WH, WL, 1);
  gemm_mfma<true, true><<<gG, 256, 0, stream>>>(XH, XL, WH, WL, bq, Q);
  // K projection (split-bf16 3-pass)
  cvt_split_kernel<<<n4x / 256, 256, 0, stream>>>(keys, XH, XL, 1);
  cvt_wt_kernel<<<gW, 256, 0, stream>>>(Wk, WH, WL, 1);
  gemm_mfma<true, true><<<gG, 256, 0, stream>>>(XH, XL, WH, WL, bk, Kp);
  // V projection (single-pass bf16)
  cvt_split_kernel<<<n4x / 256, 256, 0, stream>>>(values, XH, XL, 0);
  cvt_wt_kernel<<<gW, 256, 0, stream>>>(Wv, WH, WL, 0);
  gemm_mfma<false, true><<<gG, 256, 0, stream>>>(XH, XH, WH, WH, bv, Vp);

  m_kernel<<<BHROWS / 4, 256, 0, stream>>>(Q, Kp, index_sample, M);
  topk_kernel<<<NB * NH, 1024, 0, stream>>>(M, Mtop);
  vsum1_kernel<<<dim3(NB * NH, VCH), 256, 0, stream>>>(Vp, vpart);
  vsum2_kernel<<<NB * NH, 64, 0, stream>>>(vpart, Vsum);
  ctxinit_kernel<<<(ROWS * DM / 4) / 256, 256, 0, stream>>>(Vsum, ctxT);
  scores_kernel<<<dim3(NB * NH, SEQ / 256), 256, 0, stream>>>(Q, Kp, Mtop, scores);
  softmax_kernel<<<NB * NH * NT, 256, 0, stream>>>(scores);
  pv_partial_kernel<<<dim3(NB * NH, NSC), 256, 0, stream>>>(scores, Vp, updp);
  reduce_scatter_kernel<<<dim3(NB * NH, NT / 4), 256, 0, stream>>>(updp, Mtop, ctxT);

  // Output projection (single-pass bf16)
  cvt_split_kernel<<<n4x / 256, 256, 0, stream>>>(ctxT, CH, CH, 0);
  cvt_wt_kernel<<<gW, 256, 0, stream>>>(Wo, WoH, WoH, 0);
  gemm_mfma<false, false><<<gG, 256, 0, stream>>>(CH, CH, WoH, WoH, bo, out);
}